// Round 10
// baseline (189.040 us; speedup 1.0000x reference)
//
#include <hip/hip_runtime.h>

// Problem constants (B=2, C=256, H=W=48, d_model=256, 8 heads, d_k=32)
// Inputs/outputs fp32. Internals bf16; all matmuls + attention on MFMA.
// Wb / xt / aot live in MFMA-fragment-order swizzle:
//   addr(row,k) = (row>>4)*4096 + (k>>3)*128 + (row&15)*8 + (k&7)
// Distance bias in C-fragment-tile order:
//   Et[(m>>4)*144 + (q>>4)][(m&15)*16 + (q&15)]
// attn: barrier-free K-loop, register-prefetched K/V frags (one tile ahead).
#define HW 2304
#define SW 48
#define DMODEL 256
#define NHEADS 8
#define DK 32
#define BATCH 2

typedef unsigned short u16;
typedef __attribute__((ext_vector_type(8))) short short8;
typedef __attribute__((ext_vector_type(4))) float f32x4;

__device__ __forceinline__ float bf2f(u16 v) {
  union { unsigned int u; float f; } c; c.u = ((unsigned int)v) << 16; return c.f;
}
__device__ __forceinline__ float lo2f(unsigned int u) {
  union { unsigned int u; float f; } c; c.u = u << 16; return c.f;
}
__device__ __forceinline__ float hi2f(unsigned int u) {
  union { unsigned int u; float f; } c; c.u = u & 0xffff0000u; return c.f;
}
__device__ __forceinline__ u16 f2bf(float f) {
  union { unsigned int u; float f; } c; c.f = f;
  unsigned int u = c.u;
  unsigned int r = (u + 0x7FFFu + ((u >> 16) & 1u)) >> 16;
  return (u16)r;
}
// exact floor(n/48) for n in [0, 2304): magic 87382 = (2^22+32)/48
__device__ __forceinline__ int div48(int n) { return (n * 87382) >> 22; }
// fragment-order swizzle for a [rows][256] bf16 matrix
__device__ __forceinline__ int swz(int row, int k) {
  return ((row >> 4) << 12) + ((k >> 3) << 7) + ((row & 15) << 3) + (k & 7);
}

// ---------------------------------------------------------------------------
// Et bias table in C-fragment-tile order. 2304x2304 bf16. grid 2592, block 256.
__global__ __launch_bounds__(256) void eb_kernel(const float* __restrict__ lam_p,
                                                 u16* __restrict__ et) {
  int id = blockIdx.x * 256 + threadIdx.x;
  int flat = id * 8;
  int tile = flat >> 8;
  int within = flat & 255;
  int tm = tile / 144, tq = tile - tm * 144;
  int m = tm * 16 + (within >> 4);
  int q = tq * 16 + (within & 15);
  int ym = div48(m), xm = m - ym * SW;
  int yq = div48(q), xq = q - yq * SW;
  float lam = lam_p[0];
  float dy = (float)(yq - ym);
  float dy2 = dy * dy;
  u16 o[8];
#pragma unroll
  for (int j = 0; j < 8; ++j) {
    float dx = (float)(xq + j - xm);
    o[j] = f2bf(lam * __expf(-sqrtf(dy2 + dx * dx)));
  }
  *(uint4*)(et + flat) = *(const uint4*)o;
}

// ---------------------------------------------------------------------------
// prep: [0,288) transpose x -> xt (swizzled, row=n, k=c) bf16 ;
// [288,544) W fp32->bf16 swizzled, concat [q|k|v|o]. grid 544, block 256.
__global__ __launch_bounds__(256) void prep_kernel(
    const float* __restrict__ x,
    const float* __restrict__ Wq, const float* __restrict__ Wk,
    const float* __restrict__ Wv, const float* __restrict__ Wo,
    u16* __restrict__ xt, u16* __restrict__ Wb) {
  int bid = blockIdx.x;
  int t = threadIdx.x;
  if (bid < 288) {
    int b = bid / 144, r = bid % 144;
    int c0 = (r / 36) * 64, n0 = (r % 36) * 64;
    __shared__ u16 sh[64][72];  // [n][c]
#pragma unroll
    for (int p = 0; p < 4; ++p) {
      int row = (t >> 4) + p * 16;   // c
      int col4 = (t & 15) * 4;       // n
      float4 v = *(const float4*)(x + (size_t)(b * DMODEL + c0 + row) * HW +
                                  n0 + col4);
      sh[col4 + 0][row] = f2bf(v.x);
      sh[col4 + 1][row] = f2bf(v.y);
      sh[col4 + 2][row] = f2bf(v.z);
      sh[col4 + 3][row] = f2bf(v.w);
    }
    __syncthreads();
    u16* xtb = xt + (size_t)b * HW * DMODEL;
#pragma unroll
    for (int q = 0; q < 2; ++q) {
      int nrow = t >> 2;
      int c8 = (t & 3) * 8 + q * 32;
      *(uint4*)(xtb + swz(n0 + nrow, c0 + c8)) = *(const uint4*)&sh[nrow][c8];
    }
  } else {
    int idx = (bid - 288) * 1024 + t * 4;
    int which = idx >> 16, off = idx & 65535;
    int m = off >> 8, k = off & 255;
    const float* src = (which == 0) ? Wq : (which == 1) ? Wk
                       : (which == 2) ? Wv : Wo;
    float4 v = *(const float4*)(src + off);
    ushort4 ov;
    ov.x = f2bf(v.x); ov.y = f2bf(v.y); ov.z = f2bf(v.z); ov.w = f2bf(v.w);
    *(ushort4*)(Wb + which * 65536 + swz(m, k)) = ov;
  }
}

// ---------------------------------------------------------------------------
// QKV projection, LDS-free MFMA GEMM with swizzled frag loads (R8 structure).
// grid (36, 12, 2), block 256.
__global__ __launch_bounds__(256) void qkv_kernel(
    const u16* __restrict__ Wb, const u16* __restrict__ xt,
    const float* __restrict__ bq, const float* __restrict__ bk,
    const float* __restrict__ bv,
    u16* __restrict__ qt, u16* __restrict__ ktb, u16* __restrict__ vb) {
  int t = threadIdx.x;
  int w = t >> 6, lane = t & 63, lo = lane & 15, quad = lane >> 4;
  int n0 = blockIdx.x * 64;
  int mb = blockIdx.y, b = blockIdx.z;
  int which = mb >> 2;
  int mrel0 = (mb & 3) * 64;
  const u16* A = Wb + which * 65536 + ((mrel0 + w * 16) >> 4) * 4096 + lo * 8;
  const float* bias = (which == 0) ? bq : (which == 1) ? bk : bv;
  const u16* Bx = xt + (size_t)b * HW * DMODEL + lo * 8;

  f32x4 acc[4] = {{0.f, 0.f, 0.f, 0.f}, {0.f, 0.f, 0.f, 0.f},
                  {0.f, 0.f, 0.f, 0.f}, {0.f, 0.f, 0.f, 0.f}};
#pragma unroll
  for (int k0 = 0; k0 < DMODEL; k0 += 32) {
    int kblk = ((k0 >> 3) + quad) << 7;
    short8 af = *(const short8*)(A + kblk);
#pragma unroll
    for (int nt = 0; nt < 4; ++nt) {
      short8 bf_ = *(const short8*)(Bx + ((n0 + nt * 16) >> 4) * 4096 + kblk);
      acc[nt] = __builtin_amdgcn_mfma_f32_16x16x32_bf16(af, bf_, acc[nt], 0, 0, 0);
    }
  }

  int mbase = mrel0 + w * 16 + quad * 4;
  if (which == 2) {
#pragma unroll
    for (int reg = 0; reg < 4; ++reg) {
      int mrel = mbase + reg;
      float bi = bias[mrel];
      u16* dst = vb + (size_t)(b * DMODEL + mrel) * HW + n0 + lo;
#pragma unroll
      for (int nt = 0; nt < 4; ++nt) dst[nt * 16] = f2bf(acc[nt][reg] + bi);
    }
  } else {
    float sc = (which == 0) ? 0.17677669529663687f : 1.0f;
    int h = mbase >> 5, d0 = mbase & 31;
    u16* base = ((which == 0) ? qt : ktb) + (size_t)(b * NHEADS + h) * HW * DK;
    float bi[4], dv[4];
    bool usecos[4], usey[4];
#pragma unroll
    for (int reg = 0; reg < 4; ++reg) {
      int mrel = mbase + reg;
      bi[reg] = bias[mrel];
      int oo = mrel & 127;
      dv[reg] = expf(-0.07195578415606394f * (float)(oo & ~1));
      usecos[reg] = (oo & 1);
      usey[reg] = (mrel >= 128);
    }
#pragma unroll
    for (int nt = 0; nt < 4; ++nt) {
      int n = n0 + nt * 16 + lo;
      int yy = div48(n), xx = n - yy * SW;
      ushort4 ov;
      float vals[4];
#pragma unroll
      for (int reg = 0; reg < 4; ++reg) {
        float tv = (usey[reg] ? (float)yy : (float)xx) * dv[reg];
        float pe = usecos[reg] ? cosf(tv) : sinf(tv);
        vals[reg] = (acc[nt][reg] + bi[reg] + pe) * sc;
      }
      ov.x = f2bf(vals[0]); ov.y = f2bf(vals[1]);
      ov.z = f2bf(vals[2]); ov.w = f2bf(vals[3]);
      *(ushort4*)(base + (size_t)n * DK + d0) = ov;
    }
  }
}

// ---------------------------------------------------------------------------
// attn helpers: load one key-tile's K/V fragments (8x 16B/lane, all waves of a
// block read identical addresses -> L1-served after first fetch).
__device__ __forceinline__ void ld_tile(const u16* __restrict__ ktg,
                                        const u16* __restrict__ vbg, int m0,
                                        int lo, int quad,
                                        short8 kf[4], short8 vf[4]) {
#pragma unroll
  for (int t4 = 0; t4 < 4; ++t4)
    kf[t4] = *(const short8*)(ktg + (size_t)(m0 + t4 * 16 + lo) * DK + quad * 8);
#pragma unroll
  for (int ks = 0; ks < 2; ++ks) {
    vf[ks * 2 + 0] =
        *(const short8*)(vbg + (size_t)lo * HW + m0 + ks * 32 + quad * 8);
    vf[ks * 2 + 1] =
        *(const short8*)(vbg + (size_t)(16 + lo) * HW + m0 + ks * 32 + quad * 8);
  }
}

// ---------------------------------------------------------------------------
// MFMA flash attention: barrier-free, software-pipelined (K/V frags prefetched
// one tile ahead in registers). LDS holds only the per-wave P buffer.
// grid (36, 8, 2), block 256.
__global__ __launch_bounds__(256) void attn_kernel(
    const u16* __restrict__ qt, const u16* __restrict__ ktb,
    const u16* __restrict__ vb, const u16* __restrict__ et,
    u16* __restrict__ aot) {
  int t = threadIdx.x;
  int w = t >> 6;
  int lane = t & 63;
  int lo = lane & 15, quad = lane >> 4;
  int n0 = blockIdx.x * 64;
  int h = blockIdx.y, b = blockIdx.z;

  __shared__ u16 Ps[4 * 16 * 72];  // per-wave private P buffers only

  const u16* qtg = qt + (size_t)(b * NHEADS + h) * HW * DK;
  const u16* ktg = ktb + (size_t)(b * NHEADS + h) * HW * DK;
  const u16* vbg = vb + (size_t)(b * DMODEL + h * DK) * HW;

  short8 qf = *(const short8*)(qtg + (size_t)(n0 + w * 16 + lo) * DK + quad * 8);

  // bias pointer: Et[tile = tm*144 + tq][lo*16 + quad*4]
  int tq = (n0 >> 4) + w;
  const u16* etw = et + (size_t)tq * 256 + lo * 16 + quad * 4;

  f32x4 o0 = {0.f, 0.f, 0.f, 0.f}, o1 = {0.f, 0.f, 0.f, 0.f};
  float lsum[4] = {0.f, 0.f, 0.f, 0.f};
  u16* psw = Ps + w * 16 * 72;

  short8 ka[4], va[4], kb[4], vbf[4];
  ld_tile(ktg, vbg, 0, lo, quad, ka, va);

#define ATTN_BODY(M0, KF, VF)                                                  \
  {                                                                            \
    const int m0_ = (M0);                                                      \
    uint2 ebv[4];                                                              \
    _Pragma("unroll") for (int t4 = 0; t4 < 4; ++t4) ebv[t4] =                 \
        *(const uint2*)(etw + (size_t)((m0_ >> 4) + t4) * 36864);              \
    f32x4 s[4];                                                                \
    _Pragma("unroll") for (int t4 = 0; t4 < 4; ++t4) {                         \
      f32x4 z = {0.f, 0.f, 0.f, 0.f};                                          \
      s[t4] = __builtin_amdgcn_mfma_f32_16x16x32_bf16(qf, KF[t4], z, 0, 0, 0); \
    }                                                                          \
    _Pragma("unroll") for (int t4 = 0; t4 < 4; ++t4) {                         \
      float p0 = __expf(s[t4][0] + lo2f(ebv[t4].x));                           \
      float p1 = __expf(s[t4][1] + hi2f(ebv[t4].x));                           \
      float p2 = __expf(s[t4][2] + lo2f(ebv[t4].y));                           \
      float p3 = __expf(s[t4][3] + hi2f(ebv[t4].y));                           \
      lsum[0] += p0; lsum[1] += p1; lsum[2] += p2; lsum[3] += p3;              \
      psw[(quad * 4 + 0) * 72 + t4 * 16 + lo] = f2bf(p0);                      \
      psw[(quad * 4 + 1) * 72 + t4 * 16 + lo] = f2bf(p1);                      \
      psw[(quad * 4 + 2) * 72 + t4 * 16 + lo] = f2bf(p2);                      \
      psw[(quad * 4 + 3) * 72 + t4 * 16 + lo] = f2bf(p3);                      \
    }                                                                          \
    _Pragma("unroll") for (int ks = 0; ks < 2; ++ks) {                         \
      short8 af = *(const short8*)&psw[lo * 72 + ks * 32 + quad * 8];          \
      o0 = __builtin_amdgcn_mfma_f32_16x16x32_bf16(af, VF[ks * 2 + 0], o0, 0,  \
                                                   0, 0);                      \
      o1 = __builtin_amdgcn_mfma_f32_16x16x32_bf16(af, VF[ks * 2 + 1], o1, 0,  \
                                                   0, 0);                      \
    }                                                                          \
  }

  for (int kt = 0; kt < 36; kt += 2) {
    // prefetch tile kt+1 into (kb, vbf); compute tile kt from (ka, va)
    ld_tile(ktg, vbg, (kt + 1) * 64, lo, quad, kb, vbf);
    ATTN_BODY(kt * 64, ka, va);
    // prefetch tile kt+2 (kt=34 -> m0=2304: lands ~128B past vb inside d_ws,
    // garbage never used); compute tile kt+1
    ld_tile(ktg, vbg, (kt + 2) * 64, lo, quad, ka, va);
    ATTN_BODY((kt + 1) * 64, kb, vbf);
  }
#undef ATTN_BODY

#pragma unroll
  for (int d = 1; d < 16; d <<= 1) {
#pragma unroll
    for (int reg = 0; reg < 4; ++reg) lsum[reg] += __shfl_xor(lsum[reg], d);
  }

  // write aot (swizzled, row=n, k=h*32+d), d = lo and 16+lo
  u16* aog = aot + (size_t)b * HW * DMODEL;
#pragma unroll
  for (int reg = 0; reg < 4; ++reg) {
    int n = n0 + w * 16 + quad * 4 + reg;
    float inv = 1.0f / lsum[reg];
    aog[swz(n, h * DK + lo)] = f2bf(o0[reg] * inv);
    aog[swz(n, h * DK + 16 + lo)] = f2bf(o1[reg] * inv);
  }
}

// ---------------------------------------------------------------------------
// out[b][c][n] = x + gamma * (Wo ao)[c][n] + bo[c], LDS-free MFMA GEMM with
// swizzled frag loads. grid (36, 4, 2), block 256.
__global__ __launch_bounds__(256) void out_kernel(
    const float* __restrict__ x, const u16* __restrict__ Wob,
    const float* __restrict__ bo, const float* __restrict__ gp,
    const u16* __restrict__ aot, float* __restrict__ out) {
  int t = threadIdx.x;
  int w = t >> 6, lane = t & 63, lo = lane & 15, quad = lane >> 4;
  int n0 = blockIdx.x * 64;
  int c0 = blockIdx.y * 64;
  int b = blockIdx.z;
  float gamma = gp[0];
  const u16* A = Wob + ((c0 + w * 16) >> 4) * 4096 + lo * 8;
  const u16* Ba = aot + (size_t)b * HW * DMODEL + lo * 8;

  f32x4 acc[4] = {{0.f, 0.f, 0.f, 0.f}, {0.f, 0.f, 0.f, 0.f},
                  {0.f, 0.f, 0.f, 0.f}, {0.f, 0.f, 0.f, 0.f}};
#pragma unroll
  for (int k0 = 0; k0 < DMODEL; k0 += 32) {
    int kblk = ((k0 >> 3) + quad) << 7;
    short8 af = *(const short8*)(A + kblk);
#pragma unroll
    for (int nt = 0; nt < 4; ++nt) {
      short8 bf_ = *(const short8*)(Ba + ((n0 + nt * 16) >> 4) * 4096 + kblk);
      acc[nt] = __builtin_amdgcn_mfma_f32_16x16x32_bf16(af, bf_, acc[nt], 0, 0, 0);
    }
  }

#pragma unroll
  for (int reg = 0; reg < 4; ++reg) {
    int c = c0 + w * 16 + quad * 4 + reg;
    float bi = bo[c];
    const float* xs = x + (size_t)(b * DMODEL + c) * HW + n0 + lo;
    float* os = out + (size_t)(b * DMODEL + c) * HW + n0 + lo;
#pragma unroll
    for (int nt = 0; nt < 4; ++nt)
      os[nt * 16] = xs[nt * 16] + gamma * acc[nt][reg] + bi;
  }
}

// ---------------------------------------------------------------------------
extern "C" void kernel_launch(void* const* d_in, const int* in_sizes, int n_in,
                              void* d_out, int out_size, void* d_ws,
                              size_t ws_size, hipStream_t stream) {
  const float* x   = (const float*)d_in[0];
  const float* Wq  = (const float*)d_in[1];
  const float* bq  = (const float*)d_in[2];
  const float* Wk  = (const float*)d_in[3];
  const float* bk  = (const float*)d_in[4];
  const float* Wv  = (const float*)d_in[5];
  const float* bv  = (const float*)d_in[6];
  const float* Wo  = (const float*)d_in[7];
  const float* bo  = (const float*)d_in[8];
  const float* lam = (const float*)d_in[9];
  const float* gam = (const float*)d_in[10];

  // ws layout (bytes), total ~20.6 MB:
  //   (unused)   [0, 36864)
  //   Wb    bf16 [36864, 561152)      4*65536*2, [q|k|v|o], swizzled
  //   xt    bf16 [561152, 2920448)    swizzled; ALIASED with aot
  //   qt    bf16 [2920448, 5279744)
  //   ktb   bf16 [5279744, 7639040)
  //   vb    bf16 [7639040, 9998336)
  //   et    bf16 [9998336, 20615168)  2304*2304 bias, C-fragment-tile order
  char* wsb = (char*)d_ws;
  u16* Wb  = (u16*)(wsb + 36864);
  u16* xt  = (u16*)(wsb + 561152);
  u16* aot = xt;  // alias, sequential lifetime
  u16* qt  = (u16*)(wsb + 2920448);
  u16* ktb = (u16*)(wsb + 5279744);
  u16* vb  = (u16*)(wsb + 7639040);
  u16* et  = (u16*)(wsb + 9998336);
  float* out = (float*)d_out;

  eb_kernel<<<dim3(2592), 256, 0, stream>>>(lam, et);
  prep_kernel<<<dim3(544), 256, 0, stream>>>(x, Wq, Wk, Wv, Wo, xt, Wb);
  qkv_kernel<<<dim3(36, 12, BATCH), 256, 0, stream>>>(Wb, xt, bq, bk, bv,
                                                      qt, ktb, vb);
  attn_kernel<<<dim3(36, NHEADS, BATCH), 256, 0, stream>>>(qt, ktb, vb, et,
                                                           aot);
  out_kernel<<<dim3(36, 4, BATCH), 256, 0, stream>>>(x, Wb + 3 * 65536, bo, gam,
                                                     aot, out);
}

// Round 11
// 137.751 us; speedup vs baseline: 1.3723x; 1.3723x over previous
//
#include <hip/hip_runtime.h>

// Problem constants (B=2, C=256, H=W=48, d_model=256, 8 heads, d_k=32)
// Inputs/outputs fp32. Internals bf16; all matmuls + attention on MFMA.
// Wb / xt / aot in MFMA-fragment-order swizzle:
//   addr(row,k) = (row>>4)*4096 + (k>>3)*128 + (row&15)*8 + (k&7)
// Distance bias in C-fragment-tile order:
//   Et[(m>>4)*144 + (q>>4)][(m&15)*16 + (q&15)]
// attn: R9 structure (LDS-staged K/V, barriers) + 2-way split-K (fixed-max
// softmax => partials are additive). Partial O (bf16) lives in d_out (exactly
// fills it; out_kernel overwrites later); partial rowsums (f32) in ws.
#define HW 2304
#define SW 48
#define DMODEL 256
#define NHEADS 8
#define DK 32
#define BATCH 2

typedef unsigned short u16;
typedef __attribute__((ext_vector_type(8))) short short8;
typedef __attribute__((ext_vector_type(4))) float f32x4;

__device__ __forceinline__ float bf2f(u16 v) {
  union { unsigned int u; float f; } c; c.u = ((unsigned int)v) << 16; return c.f;
}
__device__ __forceinline__ float lo2f(unsigned int u) {
  union { unsigned int u; float f; } c; c.u = u << 16; return c.f;
}
__device__ __forceinline__ float hi2f(unsigned int u) {
  union { unsigned int u; float f; } c; c.u = u & 0xffff0000u; return c.f;
}
__device__ __forceinline__ u16 f2bf(float f) {
  union { unsigned int u; float f; } c; c.f = f;
  unsigned int u = c.u;
  unsigned int r = (u + 0x7FFFu + ((u >> 16) & 1u)) >> 16;
  return (u16)r;
}
// exact floor(n/48) for n in [0, 2304): magic 87382 = (2^22+32)/48
__device__ __forceinline__ int div48(int n) { return (n * 87382) >> 22; }
// fragment-order swizzle for a [rows][256] bf16 matrix
__device__ __forceinline__ int swz(int row, int k) {
  return ((row >> 4) << 12) + ((k >> 3) << 7) + ((row & 15) << 3) + (k & 7);
}

// ---------------------------------------------------------------------------
// fused prep: [0,288) transpose x -> xt (swizzled) ; [288,544) W fp32->bf16
// swizzled [q|k|v|o] ; [544,3136) Et bias table. grid 3136, block 256.
__global__ __launch_bounds__(256) void prep_kernel(
    const float* __restrict__ x,
    const float* __restrict__ Wq, const float* __restrict__ Wk,
    const float* __restrict__ Wv, const float* __restrict__ Wo,
    const float* __restrict__ lam_p,
    u16* __restrict__ xt, u16* __restrict__ Wb, u16* __restrict__ et) {
  int bid = blockIdx.x;
  int t = threadIdx.x;
  if (bid < 288) {
    int b = bid / 144, r = bid % 144;
    int c0 = (r / 36) * 64, n0 = (r % 36) * 64;
    __shared__ u16 sh[64][72];  // [n][c]
#pragma unroll
    for (int p = 0; p < 4; ++p) {
      int row = (t >> 4) + p * 16;   // c
      int col4 = (t & 15) * 4;       // n
      float4 v = *(const float4*)(x + (size_t)(b * DMODEL + c0 + row) * HW +
                                  n0 + col4);
      sh[col4 + 0][row] = f2bf(v.x);
      sh[col4 + 1][row] = f2bf(v.y);
      sh[col4 + 2][row] = f2bf(v.z);
      sh[col4 + 3][row] = f2bf(v.w);
    }
    __syncthreads();
    u16* xtb = xt + (size_t)b * HW * DMODEL;
#pragma unroll
    for (int q = 0; q < 2; ++q) {
      int nrow = t >> 2;
      int c8 = (t & 3) * 8 + q * 32;
      *(uint4*)(xtb + swz(n0 + nrow, c0 + c8)) = *(const uint4*)&sh[nrow][c8];
    }
  } else if (bid < 544) {
    int idx = (bid - 288) * 1024 + t * 4;
    int which = idx >> 16, off = idx & 65535;
    int m = off >> 8, k = off & 255;
    const float* src = (which == 0) ? Wq : (which == 1) ? Wk
                       : (which == 2) ? Wv : Wo;
    float4 v = *(const float4*)(src + off);
    ushort4 ov;
    ov.x = f2bf(v.x); ov.y = f2bf(v.y); ov.z = f2bf(v.z); ov.w = f2bf(v.w);
    *(ushort4*)(Wb + which * 65536 + swz(m, k)) = ov;
  } else {
    int id = (bid - 544) * 256 + t;
    int flat = id * 8;
    int tile = flat >> 8;
    int within = flat & 255;
    int tm = tile / 144, tq = tile - tm * 144;
    int m = tm * 16 + (within >> 4);
    int q = tq * 16 + (within & 15);
    int ym = div48(m), xm = m - ym * SW;
    int yq = div48(q), xq = q - yq * SW;
    float lam = lam_p[0];
    float dy = (float)(yq - ym);
    float dy2 = dy * dy;
    u16 o[8];
#pragma unroll
    for (int j = 0; j < 8; ++j) {
      float dx = (float)(xq + j - xm);
      o[j] = f2bf(lam * __expf(-sqrtf(dy2 + dx * dx)));
    }
    *(uint4*)(et + flat) = *(const uint4*)o;
  }
}

// ---------------------------------------------------------------------------
// QKV projection, LDS-free MFMA GEMM with swizzled frag loads (R8 structure).
// grid (36, 12, 2), block 256.
__global__ __launch_bounds__(256) void qkv_kernel(
    const u16* __restrict__ Wb, const u16* __restrict__ xt,
    const float* __restrict__ bq, const float* __restrict__ bk,
    const float* __restrict__ bv,
    u16* __restrict__ qt, u16* __restrict__ ktb, u16* __restrict__ vb) {
  int t = threadIdx.x;
  int w = t >> 6, lane = t & 63, lo = lane & 15, quad = lane >> 4;
  int n0 = blockIdx.x * 64;
  int mb = blockIdx.y, b = blockIdx.z;
  int which = mb >> 2;
  int mrel0 = (mb & 3) * 64;
  const u16* A = Wb + which * 65536 + ((mrel0 + w * 16) >> 4) * 4096 + lo * 8;
  const float* bias = (which == 0) ? bq : (which == 1) ? bk : bv;
  const u16* Bx = xt + (size_t)b * HW * DMODEL + lo * 8;

  f32x4 acc[4] = {{0.f, 0.f, 0.f, 0.f}, {0.f, 0.f, 0.f, 0.f},
                  {0.f, 0.f, 0.f, 0.f}, {0.f, 0.f, 0.f, 0.f}};
#pragma unroll
  for (int k0 = 0; k0 < DMODEL; k0 += 32) {
    int kblk = ((k0 >> 3) + quad) << 7;
    short8 af = *(const short8*)(A + kblk);
#pragma unroll
    for (int nt = 0; nt < 4; ++nt) {
      short8 bf_ = *(const short8*)(Bx + ((n0 + nt * 16) >> 4) * 4096 + kblk);
      acc[nt] = __builtin_amdgcn_mfma_f32_16x16x32_bf16(af, bf_, acc[nt], 0, 0, 0);
    }
  }

  int mbase = mrel0 + w * 16 + quad * 4;
  if (which == 2) {
#pragma unroll
    for (int reg = 0; reg < 4; ++reg) {
      int mrel = mbase + reg;
      float bi = bias[mrel];
      u16* dst = vb + (size_t)(b * DMODEL + mrel) * HW + n0 + lo;
#pragma unroll
      for (int nt = 0; nt < 4; ++nt) dst[nt * 16] = f2bf(acc[nt][reg] + bi);
    }
  } else {
    float sc = (which == 0) ? 0.17677669529663687f : 1.0f;
    int h = mbase >> 5, d0 = mbase & 31;
    u16* base = ((which == 0) ? qt : ktb) + (size_t)(b * NHEADS + h) * HW * DK;
    float bi[4], dv[4];
    bool usecos[4], usey[4];
#pragma unroll
    for (int reg = 0; reg < 4; ++reg) {
      int mrel = mbase + reg;
      bi[reg] = bias[mrel];
      int oo = mrel & 127;
      dv[reg] = expf(-0.07195578415606394f * (float)(oo & ~1));
      usecos[reg] = (oo & 1);
      usey[reg] = (mrel >= 128);
    }
#pragma unroll
    for (int nt = 0; nt < 4; ++nt) {
      int n = n0 + nt * 16 + lo;
      int yy = div48(n), xx = n - yy * SW;
      ushort4 ov;
      float vals[4];
#pragma unroll
      for (int reg = 0; reg < 4; ++reg) {
        float tv = (usey[reg] ? (float)yy : (float)xx) * dv[reg];
        float pe = usecos[reg] ? cosf(tv) : sinf(tv);
        vals[reg] = (acc[nt][reg] + bi[reg] + pe) * sc;
      }
      ov.x = f2bf(vals[0]); ov.y = f2bf(vals[1]);
      ov.z = f2bf(vals[2]); ov.w = f2bf(vals[3]);
      *(ushort4*)(base + (size_t)n * DK + d0) = ov;
    }
  }
}

// ---------------------------------------------------------------------------
// MFMA flash attention, split-K(2): R9 body, each block handles 18 key tiles.
// Partial O (bf16) -> po_o (= d_out), partial rowsums (f32) -> po_l (ws).
// grid (36, 16, 2): y = h*2 + kh. block 256.
__global__ __launch_bounds__(256) void attn_kernel(
    const u16* __restrict__ qt, const u16* __restrict__ ktb,
    const u16* __restrict__ vb, const u16* __restrict__ et,
    u16* __restrict__ po_o, float* __restrict__ po_l) {
  int t = threadIdx.x;
  int w = t >> 6;
  int lane = t & 63;
  int lo = lane & 15, quad = lane >> 4;
  int n0 = blockIdx.x * 64;
  int h = blockIdx.y >> 1, kh = blockIdx.y & 1;
  int b = blockIdx.z;

  __shared__ u16 Ks[64 * 40];
  __shared__ u16 Vs[32 * 72];
  __shared__ u16 Ps[4 * 16 * 72];

  const u16* qtg = qt + (size_t)(b * NHEADS + h) * HW * DK;
  const u16* ktg = ktb + (size_t)(b * NHEADS + h) * HW * DK;
  const u16* vbg = vb + (size_t)(b * DMODEL + h * DK) * HW;

  short8 qf = *(const short8*)(qtg + (size_t)(n0 + w * 16 + lo) * DK + quad * 8);

  int tq = (n0 >> 4) + w;
  const u16* etw = et + (size_t)tq * 256 + lo * 16 + quad * 4;

  f32x4 o0 = {0.f, 0.f, 0.f, 0.f}, o1 = {0.f, 0.f, 0.f, 0.f};
  float lsum[4] = {0.f, 0.f, 0.f, 0.f};
  u16* psw = Ps + w * 16 * 72;

  for (int kt = kh * 18; kt < kh * 18 + 18; ++kt) {
    int m0 = kt * 64;
    __syncthreads();  // prev PV reads done before restaging
    {
      int row = t >> 2, c8 = (t & 3) * 8;
      *(uint4*)&Ks[row * 40 + c8] =
          *(const uint4*)(ktg + (size_t)(m0 + row) * DK + c8);
      int dd = t >> 3, mo = (t & 7) * 8;
      *(uint4*)&Vs[dd * 72 + mo] =
          *(const uint4*)(vbg + (size_t)dd * HW + m0 + mo);
    }
    __syncthreads();

    // bias loads (independent of MFMA; 512B contiguous per wave per t4)
    uint2 ebv[4];
#pragma unroll
    for (int t4 = 0; t4 < 4; ++t4)
      ebv[t4] = *(const uint2*)(etw + (size_t)((m0 >> 4) + t4) * 36864);

    f32x4 s[4];
#pragma unroll
    for (int t4 = 0; t4 < 4; ++t4) {
      short8 kf = *(const short8*)&Ks[(t4 * 16 + lo) * 40 + quad * 8];
      f32x4 z = {0.f, 0.f, 0.f, 0.f};
      s[t4] = __builtin_amdgcn_mfma_f32_16x16x32_bf16(qf, kf, z, 0, 0, 0);
    }
#pragma unroll
    for (int t4 = 0; t4 < 4; ++t4) {
      float p0 = __expf(s[t4][0] + lo2f(ebv[t4].x));
      float p1 = __expf(s[t4][1] + hi2f(ebv[t4].x));
      float p2 = __expf(s[t4][2] + lo2f(ebv[t4].y));
      float p3 = __expf(s[t4][3] + hi2f(ebv[t4].y));
      lsum[0] += p0; lsum[1] += p1; lsum[2] += p2; lsum[3] += p3;
      psw[(quad * 4 + 0) * 72 + t4 * 16 + lo] = f2bf(p0);
      psw[(quad * 4 + 1) * 72 + t4 * 16 + lo] = f2bf(p1);
      psw[(quad * 4 + 2) * 72 + t4 * 16 + lo] = f2bf(p2);
      psw[(quad * 4 + 3) * 72 + t4 * 16 + lo] = f2bf(p3);
    }
#pragma unroll
    for (int ks = 0; ks < 2; ++ks) {
      short8 af = *(const short8*)&psw[lo * 72 + ks * 32 + quad * 8];
      short8 v0 = *(const short8*)&Vs[lo * 72 + ks * 32 + quad * 8];
      o0 = __builtin_amdgcn_mfma_f32_16x16x32_bf16(af, v0, o0, 0, 0, 0);
      short8 v1 = *(const short8*)&Vs[(16 + lo) * 72 + ks * 32 + quad * 8];
      o1 = __builtin_amdgcn_mfma_f32_16x16x32_bf16(af, v1, o1, 0, 0, 0);
    }
  }

#pragma unroll
  for (int d = 1; d < 16; d <<= 1) {
#pragma unroll
    for (int reg = 0; reg < 4; ++reg) lsum[reg] += __shfl_xor(lsum[reg], d);
  }

  // store partials: slot = (b*8+h)*36 + qtile; per-wave region 1024B in po_o
  int slot = (b * NHEADS + h) * 36 + blockIdx.x;
  u16* pw = po_o + (size_t)(kh * 576 + slot) * 2048 + w * 512;  // u16 units
  ushort4 s0, s1;
  s0.x = f2bf(o0[0]); s0.y = f2bf(o0[1]); s0.z = f2bf(o0[2]); s0.w = f2bf(o0[3]);
  s1.x = f2bf(o1[0]); s1.y = f2bf(o1[1]); s1.z = f2bf(o1[2]); s1.w = f2bf(o1[3]);
  *(ushort4*)(pw + lane * 4) = s0;
  *(ushort4*)(pw + 256 + lane * 4) = s1;
  if (lo == 0) {
    float4 lv = make_float4(lsum[0], lsum[1], lsum[2], lsum[3]);
    *(float4*)(po_l + (size_t)(kh * 576 + slot) * 64 + w * 16 + quad * 4) = lv;
  }
}

// ---------------------------------------------------------------------------
// reduce: sum the two split-K partials, normalize, write aot (swizzled).
// grid (36, 8, 2), block 256.
__global__ __launch_bounds__(256) void reduce_kernel(
    const u16* __restrict__ po_o, const float* __restrict__ po_l,
    u16* __restrict__ aot) {
  int t = threadIdx.x;
  int w = t >> 6, lane = t & 63, lo = lane & 15, quad = lane >> 4;
  int qt_ = blockIdx.x, h = blockIdx.y, b = blockIdx.z;
  int slot = (b * NHEADS + h) * 36 + qt_;

  const u16* p0 = po_o + (size_t)slot * 2048 + w * 512;
  const u16* p1 = p0 + 576 * 2048;
  ushort4 a0 = *(const ushort4*)(p0 + lane * 4);
  ushort4 b0 = *(const ushort4*)(p1 + lane * 4);
  ushort4 a1 = *(const ushort4*)(p0 + 256 + lane * 4);
  ushort4 b1 = *(const ushort4*)(p1 + 256 + lane * 4);

  const float* l0p = po_l + (size_t)slot * 64 + w * 16 + quad * 4;
  float4 l0 = *(const float4*)l0p;
  float4 l1 = *(const float4*)(l0p + 576 * 64);
  float inv[4];
  inv[0] = 1.0f / (l0.x + l1.x);
  inv[1] = 1.0f / (l0.y + l1.y);
  inv[2] = 1.0f / (l0.z + l1.z);
  inv[3] = 1.0f / (l0.w + l1.w);

  u16 av0[4] = {(u16)a0.x, (u16)a0.y, (u16)a0.z, (u16)a0.w};
  u16 bv0[4] = {(u16)b0.x, (u16)b0.y, (u16)b0.z, (u16)b0.w};
  u16 av1[4] = {(u16)a1.x, (u16)a1.y, (u16)a1.z, (u16)a1.w};
  u16 bv1[4] = {(u16)b1.x, (u16)b1.y, (u16)b1.z, (u16)b1.w};

  u16* aog = aot + (size_t)b * HW * DMODEL;
#pragma unroll
  for (int reg = 0; reg < 4; ++reg) {
    int n = qt_ * 64 + w * 16 + quad * 4 + reg;
    aog[swz(n, h * DK + lo)] = f2bf((bf2f(av0[reg]) + bf2f(bv0[reg])) * inv[reg]);
    aog[swz(n, h * DK + 16 + lo)] =
        f2bf((bf2f(av1[reg]) + bf2f(bv1[reg])) * inv[reg]);
  }
}

// ---------------------------------------------------------------------------
// out[b][c][n] = x + gamma * (Wo ao)[c][n] + bo[c], LDS-free MFMA GEMM with
// swizzled frag loads. grid (36, 4, 2), block 256. Overwrites all of d_out.
__global__ __launch_bounds__(256) void out_kernel(
    const float* __restrict__ x, const u16* __restrict__ Wob,
    const float* __restrict__ bo, const float* __restrict__ gp,
    const u16* __restrict__ aot, float* __restrict__ out) {
  int t = threadIdx.x;
  int w = t >> 6, lane = t & 63, lo = lane & 15, quad = lane >> 4;
  int n0 = blockIdx.x * 64;
  int c0 = blockIdx.y * 64;
  int b = blockIdx.z;
  float gamma = gp[0];
  const u16* A = Wob + ((c0 + w * 16) >> 4) * 4096 + lo * 8;
  const u16* Ba = aot + (size_t)b * HW * DMODEL + lo * 8;

  f32x4 acc[4] = {{0.f, 0.f, 0.f, 0.f}, {0.f, 0.f, 0.f, 0.f},
                  {0.f, 0.f, 0.f, 0.f}, {0.f, 0.f, 0.f, 0.f}};
#pragma unroll
  for (int k0 = 0; k0 < DMODEL; k0 += 32) {
    int kblk = ((k0 >> 3) + quad) << 7;
    short8 af = *(const short8*)(A + kblk);
#pragma unroll
    for (int nt = 0; nt < 4; ++nt) {
      short8 bf_ = *(const short8*)(Ba + ((n0 + nt * 16) >> 4) * 4096 + kblk);
      acc[nt] = __builtin_amdgcn_mfma_f32_16x16x32_bf16(af, bf_, acc[nt], 0, 0, 0);
    }
  }

#pragma unroll
  for (int reg = 0; reg < 4; ++reg) {
    int c = c0 + w * 16 + quad * 4 + reg;
    float bi = bo[c];
    const float* xs = x + (size_t)(b * DMODEL + c) * HW + n0 + lo;
    float* os = out + (size_t)(b * DMODEL + c) * HW + n0 + lo;
#pragma unroll
    for (int nt = 0; nt < 4; ++nt)
      os[nt * 16] = xs[nt * 16] + gamma * acc[nt][reg] + bi;
  }
}

// ---------------------------------------------------------------------------
extern "C" void kernel_launch(void* const* d_in, const int* in_sizes, int n_in,
                              void* d_out, int out_size, void* d_ws,
                              size_t ws_size, hipStream_t stream) {
  const float* x   = (const float*)d_in[0];
  const float* Wq  = (const float*)d_in[1];
  const float* bq  = (const float*)d_in[2];
  const float* Wk  = (const float*)d_in[3];
  const float* bk  = (const float*)d_in[4];
  const float* Wv  = (const float*)d_in[5];
  const float* bv  = (const float*)d_in[6];
  const float* Wo  = (const float*)d_in[7];
  const float* bo  = (const float*)d_in[8];
  const float* lam = (const float*)d_in[9];
  const float* gam = (const float*)d_in[10];

  // ws layout (bytes), total 20,910,080 (< 21.27 MB evidenced-clean from R0):
  //   (unused)   [0, 36864)
  //   Wb    bf16 [36864, 561152)      4*65536*2, [q|k|v|o], swizzled
  //   xt    bf16 [561152, 2920448)    swizzled; ALIASED with aot
  //   qt    bf16 [2920448, 5279744)
  //   ktb   bf16 [5279744, 7639040)
  //   vb    bf16 [7639040, 9998336)
  //   et    bf16 [9998336, 20615168)  2304*2304 bias, C-fragment-tile order
  //   po_l  f32  [20615168, 20910080) split-K partial rowsums
  // Partial O (bf16, 4,718,592 B) lives in d_out — exactly fills it; the
  // final out_kernel overwrites every element of d_out afterwards.
  char* wsb = (char*)d_ws;
  u16* Wb  = (u16*)(wsb + 36864);
  u16* xt  = (u16*)(wsb + 561152);
  u16* aot = xt;  // alias, sequential lifetime
  u16* qt  = (u16*)(wsb + 2920448);
  u16* ktb = (u16*)(wsb + 5279744);
  u16* vb  = (u16*)(wsb + 7639040);
  u16* et  = (u16*)(wsb + 9998336);
  float* po_l = (float*)(wsb + 20615168);
  u16* po_o = (u16*)d_out;
  float* out = (float*)d_out;

  prep_kernel<<<dim3(3136), 256, 0, stream>>>(x, Wq, Wk, Wv, Wo, lam,
                                              xt, Wb, et);
  qkv_kernel<<<dim3(36, 12, BATCH), 256, 0, stream>>>(Wb, xt, bq, bk, bv,
                                                      qt, ktb, vb);
  attn_kernel<<<dim3(36, 16, BATCH), 256, 0, stream>>>(qt, ktb, vb, et,
                                                       po_o, po_l);
  reduce_kernel<<<dim3(36, 8, BATCH), 256, 0, stream>>>(po_o, po_l, aot);
  out_kernel<<<dim3(36, 4, BATCH), 256, 0, stream>>>(x, Wb + 3 * 65536, bo, gam,
                                                     aot, out);
}

// Round 12
// 136.894 us; speedup vs baseline: 1.3809x; 1.0063x over previous
//
#include <hip/hip_runtime.h>

// Problem constants (B=2, C=256, H=W=48, d_model=256, 8 heads, d_k=32)
// Inputs/outputs fp32. Internals bf16; all matmuls + attention on MFMA.
// Wb / xt / aot in MFMA-fragment-order swizzle:
//   addr(row,k) = (row>>4)*4096 + (k>>3)*128 + (row&15)*8 + (k&7)
// Distance bias in C-fragment-tile order:
//   Et[(m>>4)*144 + (q>>4)][(m&15)*16 + (q&15)]
// attn: LDS-staged K/V + 4-way split-K (fixed-max softmax => partials
// additive). Partials live in ws (ws_size ~268 MB per R11 fill evidence).
#define HW 2304
#define SW 48
#define DMODEL 256
#define NHEADS 8
#define DK 32
#define BATCH 2

typedef unsigned short u16;
typedef __attribute__((ext_vector_type(8))) short short8;
typedef __attribute__((ext_vector_type(4))) float f32x4;

__device__ __forceinline__ float bf2f(u16 v) {
  union { unsigned int u; float f; } c; c.u = ((unsigned int)v) << 16; return c.f;
}
__device__ __forceinline__ float lo2f(unsigned int u) {
  union { unsigned int u; float f; } c; c.u = u << 16; return c.f;
}
__device__ __forceinline__ float hi2f(unsigned int u) {
  union { unsigned int u; float f; } c; c.u = u & 0xffff0000u; return c.f;
}
__device__ __forceinline__ u16 f2bf(float f) {
  union { unsigned int u; float f; } c; c.f = f;
  unsigned int u = c.u;
  unsigned int r = (u + 0x7FFFu + ((u >> 16) & 1u)) >> 16;
  return (u16)r;
}
// exact floor(n/48) for n in [0, 2304): magic 87382 = (2^22+32)/48
__device__ __forceinline__ int div48(int n) { return (n * 87382) >> 22; }
// fragment-order swizzle for a [rows][256] bf16 matrix
__device__ __forceinline__ int swz(int row, int k) {
  return ((row >> 4) << 12) + ((k >> 3) << 7) + ((row & 15) << 3) + (k & 7);
}

// ---------------------------------------------------------------------------
// fused prep: [0,288) transpose x -> xt (swizzled) ; [288,544) W fp32->bf16
// swizzled [q|k|v|o] ; [544,3136) Et bias table. grid 3136, block 256.
__global__ __launch_bounds__(256) void prep_kernel(
    const float* __restrict__ x,
    const float* __restrict__ Wq, const float* __restrict__ Wk,
    const float* __restrict__ Wv, const float* __restrict__ Wo,
    const float* __restrict__ lam_p,
    u16* __restrict__ xt, u16* __restrict__ Wb, u16* __restrict__ et) {
  int bid = blockIdx.x;
  int t = threadIdx.x;
  if (bid < 288) {
    int b = bid / 144, r = bid % 144;
    int c0 = (r / 36) * 64, n0 = (r % 36) * 64;
    __shared__ u16 sh[64][72];  // [n][c]
#pragma unroll
    for (int p = 0; p < 4; ++p) {
      int row = (t >> 4) + p * 16;   // c
      int col4 = (t & 15) * 4;       // n
      float4 v = *(const float4*)(x + (size_t)(b * DMODEL + c0 + row) * HW +
                                  n0 + col4);
      sh[col4 + 0][row] = f2bf(v.x);
      sh[col4 + 1][row] = f2bf(v.y);
      sh[col4 + 2][row] = f2bf(v.z);
      sh[col4 + 3][row] = f2bf(v.w);
    }
    __syncthreads();
    u16* xtb = xt + (size_t)b * HW * DMODEL;
#pragma unroll
    for (int q = 0; q < 2; ++q) {
      int nrow = t >> 2;
      int c8 = (t & 3) * 8 + q * 32;
      *(uint4*)(xtb + swz(n0 + nrow, c0 + c8)) = *(const uint4*)&sh[nrow][c8];
    }
  } else if (bid < 544) {
    int idx = (bid - 288) * 1024 + t * 4;
    int which = idx >> 16, off = idx & 65535;
    int m = off >> 8, k = off & 255;
    const float* src = (which == 0) ? Wq : (which == 1) ? Wk
                       : (which == 2) ? Wv : Wo;
    float4 v = *(const float4*)(src + off);
    ushort4 ov;
    ov.x = f2bf(v.x); ov.y = f2bf(v.y); ov.z = f2bf(v.z); ov.w = f2bf(v.w);
    *(ushort4*)(Wb + which * 65536 + swz(m, k)) = ov;
  } else {
    int id = (bid - 544) * 256 + t;
    int flat = id * 8;
    int tile = flat >> 8;
    int within = flat & 255;
    int tm = tile / 144, tq = tile - tm * 144;
    int m = tm * 16 + (within >> 4);
    int q = tq * 16 + (within & 15);
    int ym = div48(m), xm = m - ym * SW;
    int yq = div48(q), xq = q - yq * SW;
    float lam = lam_p[0];
    float dy = (float)(yq - ym);
    float dy2 = dy * dy;
    u16 o[8];
#pragma unroll
    for (int j = 0; j < 8; ++j) {
      float dx = (float)(xq + j - xm);
      o[j] = f2bf(lam * __expf(-sqrtf(dy2 + dx * dx)));
    }
    *(uint4*)(et + flat) = *(const uint4*)o;
  }
}

// ---------------------------------------------------------------------------
// QKV projection, LDS-free MFMA GEMM with swizzled frag loads (R8 structure).
// grid (36, 12, 2), block 256.
__global__ __launch_bounds__(256) void qkv_kernel(
    const u16* __restrict__ Wb, const u16* __restrict__ xt,
    const float* __restrict__ bq, const float* __restrict__ bk,
    const float* __restrict__ bv,
    u16* __restrict__ qt, u16* __restrict__ ktb, u16* __restrict__ vb) {
  int t = threadIdx.x;
  int w = t >> 6, lane = t & 63, lo = lane & 15, quad = lane >> 4;
  int n0 = blockIdx.x * 64;
  int mb = blockIdx.y, b = blockIdx.z;
  int which = mb >> 2;
  int mrel0 = (mb & 3) * 64;
  const u16* A = Wb + which * 65536 + ((mrel0 + w * 16) >> 4) * 4096 + lo * 8;
  const float* bias = (which == 0) ? bq : (which == 1) ? bk : bv;
  const u16* Bx = xt + (size_t)b * HW * DMODEL + lo * 8;

  f32x4 acc[4] = {{0.f, 0.f, 0.f, 0.f}, {0.f, 0.f, 0.f, 0.f},
                  {0.f, 0.f, 0.f, 0.f}, {0.f, 0.f, 0.f, 0.f}};
#pragma unroll
  for (int k0 = 0; k0 < DMODEL; k0 += 32) {
    int kblk = ((k0 >> 3) + quad) << 7;
    short8 af = *(const short8*)(A + kblk);
#pragma unroll
    for (int nt = 0; nt < 4; ++nt) {
      short8 bf_ = *(const short8*)(Bx + ((n0 + nt * 16) >> 4) * 4096 + kblk);
      acc[nt] = __builtin_amdgcn_mfma_f32_16x16x32_bf16(af, bf_, acc[nt], 0, 0, 0);
    }
  }

  int mbase = mrel0 + w * 16 + quad * 4;
  if (which == 2) {
#pragma unroll
    for (int reg = 0; reg < 4; ++reg) {
      int mrel = mbase + reg;
      float bi = bias[mrel];
      u16* dst = vb + (size_t)(b * DMODEL + mrel) * HW + n0 + lo;
#pragma unroll
      for (int nt = 0; nt < 4; ++nt) dst[nt * 16] = f2bf(acc[nt][reg] + bi);
    }
  } else {
    float sc = (which == 0) ? 0.17677669529663687f : 1.0f;
    int h = mbase >> 5, d0 = mbase & 31;
    u16* base = ((which == 0) ? qt : ktb) + (size_t)(b * NHEADS + h) * HW * DK;
    float bi[4], dv[4];
    bool usecos[4], usey[4];
#pragma unroll
    for (int reg = 0; reg < 4; ++reg) {
      int mrel = mbase + reg;
      bi[reg] = bias[mrel];
      int oo = mrel & 127;
      dv[reg] = expf(-0.07195578415606394f * (float)(oo & ~1));
      usecos[reg] = (oo & 1);
      usey[reg] = (mrel >= 128);
    }
#pragma unroll
    for (int nt = 0; nt < 4; ++nt) {
      int n = n0 + nt * 16 + lo;
      int yy = div48(n), xx = n - yy * SW;
      ushort4 ov;
      float vals[4];
#pragma unroll
      for (int reg = 0; reg < 4; ++reg) {
        float tv = (usey[reg] ? (float)yy : (float)xx) * dv[reg];
        float pe = usecos[reg] ? cosf(tv) : sinf(tv);
        vals[reg] = (acc[nt][reg] + bi[reg] + pe) * sc;
      }
      ov.x = f2bf(vals[0]); ov.y = f2bf(vals[1]);
      ov.z = f2bf(vals[2]); ov.w = f2bf(vals[3]);
      *(ushort4*)(base + (size_t)n * DK + d0) = ov;
    }
  }
}

// ---------------------------------------------------------------------------
// MFMA flash attention, split-K(4): each block handles 9 key tiles.
// Partial O (bf16) -> po_o (ws), partial rowsums (f32) -> po_l (ws).
// grid (36, 32, 2): y = h*4 + kh. block 256.
__global__ __launch_bounds__(256) void attn_kernel(
    const u16* __restrict__ qt, const u16* __restrict__ ktb,
    const u16* __restrict__ vb, const u16* __restrict__ et,
    u16* __restrict__ po_o, float* __restrict__ po_l) {
  int t = threadIdx.x;
  int w = t >> 6;
  int lane = t & 63;
  int lo = lane & 15, quad = lane >> 4;
  int n0 = blockIdx.x * 64;
  int h = blockIdx.y >> 2, kh = blockIdx.y & 3;
  int b = blockIdx.z;

  __shared__ u16 Ks[64 * 40];
  __shared__ u16 Vs[32 * 72];
  __shared__ u16 Ps[4 * 16 * 72];

  const u16* qtg = qt + (size_t)(b * NHEADS + h) * HW * DK;
  const u16* ktg = ktb + (size_t)(b * NHEADS + h) * HW * DK;
  const u16* vbg = vb + (size_t)(b * DMODEL + h * DK) * HW;

  short8 qf = *(const short8*)(qtg + (size_t)(n0 + w * 16 + lo) * DK + quad * 8);

  int tq = (n0 >> 4) + w;
  const u16* etw = et + (size_t)tq * 256 + lo * 16 + quad * 4;

  f32x4 o0 = {0.f, 0.f, 0.f, 0.f}, o1 = {0.f, 0.f, 0.f, 0.f};
  float lsum[4] = {0.f, 0.f, 0.f, 0.f};
  u16* psw = Ps + w * 16 * 72;

  for (int kt = kh * 9; kt < kh * 9 + 9; ++kt) {
    int m0 = kt * 64;
    __syncthreads();  // prev PV reads done before restaging
    {
      int row = t >> 2, c8 = (t & 3) * 8;
      *(uint4*)&Ks[row * 40 + c8] =
          *(const uint4*)(ktg + (size_t)(m0 + row) * DK + c8);
      int dd = t >> 3, mo = (t & 7) * 8;
      *(uint4*)&Vs[dd * 72 + mo] =
          *(const uint4*)(vbg + (size_t)dd * HW + m0 + mo);
    }
    __syncthreads();

    // bias loads (independent of MFMA; 512B contiguous per wave per t4)
    uint2 ebv[4];
#pragma unroll
    for (int t4 = 0; t4 < 4; ++t4)
      ebv[t4] = *(const uint2*)(etw + (size_t)((m0 >> 4) + t4) * 36864);

    f32x4 s[4];
#pragma unroll
    for (int t4 = 0; t4 < 4; ++t4) {
      short8 kf = *(const short8*)&Ks[(t4 * 16 + lo) * 40 + quad * 8];
      f32x4 z = {0.f, 0.f, 0.f, 0.f};
      s[t4] = __builtin_amdgcn_mfma_f32_16x16x32_bf16(qf, kf, z, 0, 0, 0);
    }
#pragma unroll
    for (int t4 = 0; t4 < 4; ++t4) {
      float p0 = __expf(s[t4][0] + lo2f(ebv[t4].x));
      float p1 = __expf(s[t4][1] + hi2f(ebv[t4].x));
      float p2 = __expf(s[t4][2] + lo2f(ebv[t4].y));
      float p3 = __expf(s[t4][3] + hi2f(ebv[t4].y));
      lsum[0] += p0; lsum[1] += p1; lsum[2] += p2; lsum[3] += p3;
      psw[(quad * 4 + 0) * 72 + t4 * 16 + lo] = f2bf(p0);
      psw[(quad * 4 + 1) * 72 + t4 * 16 + lo] = f2bf(p1);
      psw[(quad * 4 + 2) * 72 + t4 * 16 + lo] = f2bf(p2);
      psw[(quad * 4 + 3) * 72 + t4 * 16 + lo] = f2bf(p3);
    }
#pragma unroll
    for (int ks = 0; ks < 2; ++ks) {
      short8 af = *(const short8*)&psw[lo * 72 + ks * 32 + quad * 8];
      short8 v0 = *(const short8*)&Vs[lo * 72 + ks * 32 + quad * 8];
      o0 = __builtin_amdgcn_mfma_f32_16x16x32_bf16(af, v0, o0, 0, 0, 0);
      short8 v1 = *(const short8*)&Vs[(16 + lo) * 72 + ks * 32 + quad * 8];
      o1 = __builtin_amdgcn_mfma_f32_16x16x32_bf16(af, v1, o1, 0, 0, 0);
    }
  }

#pragma unroll
  for (int d = 1; d < 16; d <<= 1) {
#pragma unroll
    for (int reg = 0; reg < 4; ++reg) lsum[reg] += __shfl_xor(lsum[reg], d);
  }

  // store partials: slot = (b*8+h)*36 + qtile; per-wave region 1024B
  int slot = (b * NHEADS + h) * 36 + blockIdx.x;
  u16* pw = po_o + (size_t)(kh * 576 + slot) * 2048 + w * 512;  // u16 units
  ushort4 s0, s1;
  s0.x = f2bf(o0[0]); s0.y = f2bf(o0[1]); s0.z = f2bf(o0[2]); s0.w = f2bf(o0[3]);
  s1.x = f2bf(o1[0]); s1.y = f2bf(o1[1]); s1.z = f2bf(o1[2]); s1.w = f2bf(o1[3]);
  *(ushort4*)(pw + lane * 4) = s0;
  *(ushort4*)(pw + 256 + lane * 4) = s1;
  if (lo == 0) {
    float4 lv = make_float4(lsum[0], lsum[1], lsum[2], lsum[3]);
    *(float4*)(po_l + (size_t)(kh * 576 + slot) * 64 + w * 16 + quad * 4) = lv;
  }
}

// ---------------------------------------------------------------------------
// reduce: sum the four split-K partials, normalize, write aot (swizzled).
// grid (36, 8, 2), block 256.
__global__ __launch_bounds__(256) void reduce_kernel(
    const u16* __restrict__ po_o, const float* __restrict__ po_l,
    u16* __restrict__ aot) {
  int t = threadIdx.x;
  int w = t >> 6, lane = t & 63, lo = lane & 15, quad = lane >> 4;
  int qt_ = blockIdx.x, h = blockIdx.y, b = blockIdx.z;
  int slot = (b * NHEADS + h) * 36 + qt_;

  float s0[4] = {0.f, 0.f, 0.f, 0.f}, s1[4] = {0.f, 0.f, 0.f, 0.f};
  float lt[4] = {0.f, 0.f, 0.f, 0.f};
#pragma unroll
  for (int kh = 0; kh < 4; ++kh) {
    const u16* p = po_o + (size_t)(kh * 576 + slot) * 2048 + w * 512;
    ushort4 a0 = *(const ushort4*)(p + lane * 4);
    ushort4 a1 = *(const ushort4*)(p + 256 + lane * 4);
    s0[0] += bf2f(a0.x); s0[1] += bf2f(a0.y);
    s0[2] += bf2f(a0.z); s0[3] += bf2f(a0.w);
    s1[0] += bf2f(a1.x); s1[1] += bf2f(a1.y);
    s1[2] += bf2f(a1.z); s1[3] += bf2f(a1.w);
    float4 lv = *(const float4*)(po_l + (size_t)(kh * 576 + slot) * 64 +
                                 w * 16 + quad * 4);
    lt[0] += lv.x; lt[1] += lv.y; lt[2] += lv.z; lt[3] += lv.w;
  }

  u16* aog = aot + (size_t)b * HW * DMODEL;
#pragma unroll
  for (int reg = 0; reg < 4; ++reg) {
    float inv = 1.0f / lt[reg];
    int n = qt_ * 64 + w * 16 + quad * 4 + reg;
    aog[swz(n, h * DK + lo)] = f2bf(s0[reg] * inv);
    aog[swz(n, h * DK + 16 + lo)] = f2bf(s1[reg] * inv);
  }
}

// ---------------------------------------------------------------------------
// out[b][c][n] = x + gamma * (Wo ao)[c][n] + bo[c], LDS-free MFMA GEMM with
// swizzled frag loads. grid (36, 4, 2), block 256.
__global__ __launch_bounds__(256) void out_kernel(
    const float* __restrict__ x, const u16* __restrict__ Wob,
    const float* __restrict__ bo, const float* __restrict__ gp,
    const u16* __restrict__ aot, float* __restrict__ out) {
  int t = threadIdx.x;
  int w = t >> 6, lane = t & 63, lo = lane & 15, quad = lane >> 4;
  int n0 = blockIdx.x * 64;
  int c0 = blockIdx.y * 64;
  int b = blockIdx.z;
  float gamma = gp[0];
  const u16* A = Wob + ((c0 + w * 16) >> 4) * 4096 + lo * 8;
  const u16* Ba = aot + (size_t)b * HW * DMODEL + lo * 8;

  f32x4 acc[4] = {{0.f, 0.f, 0.f, 0.f}, {0.f, 0.f, 0.f, 0.f},
                  {0.f, 0.f, 0.f, 0.f}, {0.f, 0.f, 0.f, 0.f}};
#pragma unroll
  for (int k0 = 0; k0 < DMODEL; k0 += 32) {
    int kblk = ((k0 >> 3) + quad) << 7;
    short8 af = *(const short8*)(A + kblk);
#pragma unroll
    for (int nt = 0; nt < 4; ++nt) {
      short8 bf_ = *(const short8*)(Ba + ((n0 + nt * 16) >> 4) * 4096 + kblk);
      acc[nt] = __builtin_amdgcn_mfma_f32_16x16x32_bf16(af, bf_, acc[nt], 0, 0, 0);
    }
  }

#pragma unroll
  for (int reg = 0; reg < 4; ++reg) {
    int c = c0 + w * 16 + quad * 4 + reg;
    float bi = bo[c];
    const float* xs = x + (size_t)(b * DMODEL + c) * HW + n0 + lo;
    float* os = out + (size_t)(b * DMODEL + c) * HW + n0 + lo;
#pragma unroll
    for (int nt = 0; nt < 4; ++nt)
      os[nt * 16] = xs[nt * 16] + gamma * acc[nt][reg] + bi;
  }
}

// ---------------------------------------------------------------------------
extern "C" void kernel_launch(void* const* d_in, const int* in_sizes, int n_in,
                              void* d_out, int out_size, void* d_ws,
                              size_t ws_size, hipStream_t stream) {
  const float* x   = (const float*)d_in[0];
  const float* Wq  = (const float*)d_in[1];
  const float* bq  = (const float*)d_in[2];
  const float* Wk  = (const float*)d_in[3];
  const float* bk  = (const float*)d_in[4];
  const float* Wv  = (const float*)d_in[5];
  const float* bv  = (const float*)d_in[6];
  const float* Wo  = (const float*)d_in[7];
  const float* bo  = (const float*)d_in[8];
  const float* lam = (const float*)d_in[9];
  const float* gam = (const float*)d_in[10];

  // ws layout (bytes); ws_size ~268 MB (R11 fill-dispatch evidence):
  //   (unused)   [0, 36864)
  //   Wb    bf16 [36864, 561152)      4*65536*2, [q|k|v|o], swizzled
  //   xt    bf16 [561152, 2920448)    swizzled; ALIASED with aot
  //   qt    bf16 [2920448, 5279744)
  //   ktb   bf16 [5279744, 7639040)
  //   vb    bf16 [7639040, 9998336)
  //   et    bf16 [9998336, 20615168)  2304*2304 bias, C-fragment-tile order
  //   po_o  bf16 [20615168, 30052352) split-K(4) partial O
  //   po_l  f32  [30052352, 30642176) split-K(4) partial rowsums
  char* wsb = (char*)d_ws;
  u16* Wb  = (u16*)(wsb + 36864);
  u16* xt  = (u16*)(wsb + 561152);
  u16* aot = xt;  // alias, sequential lifetime
  u16* qt  = (u16*)(wsb + 2920448);
  u16* ktb = (u16*)(wsb + 5279744);
  u16* vb  = (u16*)(wsb + 7639040);
  u16* et  = (u16*)(wsb + 9998336);
  u16* po_o = (u16*)(wsb + 20615168);
  float* po_l = (float*)(wsb + 30052352);
  float* out = (float*)d_out;

  prep_kernel<<<dim3(3136), 256, 0, stream>>>(x, Wq, Wk, Wv, Wo, lam,
                                              xt, Wb, et);
  qkv_kernel<<<dim3(36, 12, BATCH), 256, 0, stream>>>(Wb, xt, bq, bk, bv,
                                                      qt, ktb, vb);
  attn_kernel<<<dim3(36, 32, BATCH), 256, 0, stream>>>(qt, ktb, vb, et,
                                                       po_o, po_l);
  reduce_kernel<<<dim3(36, 8, BATCH), 256, 0, stream>>>(po_o, po_l, aot);
  out_kernel<<<dim3(36, 4, BATCH), 256, 0, stream>>>(x, Wb + 3 * 65536, bo, gam,
                                                     aot, out);
}

// Round 13
// 134.723 us; speedup vs baseline: 1.4032x; 1.0161x over previous
//
#include <hip/hip_runtime.h>

// Problem constants (B=2, C=256, H=W=48, d_model=256, 8 heads, d_k=32)
// Inputs/outputs fp32. Internals bf16; all matmuls + attention on MFMA.
// Wb / xt / aot in MFMA-fragment-order swizzle:
//   addr(row,k) = (row>>4)*4096 + (k>>3)*128 + (row&15)*8 + (k&7)
// Distance bias in fragment-tile order: Et[T1*144+T2][(i1)*16+i2] =
//   lam*exp(-dist(pos(16*T1+i1), pos(16*T2+i2)))  (symmetric function)
// attn: S^T orientation with permuted K-row staging => P stays in REGISTERS
// (C-layout of QK^T == B-operand layout of PV). No P LDS round-trip.
// 4-way split-K (fixed-max softmax => partials additive).
#define HW 2304
#define SW 48
#define DMODEL 256
#define NHEADS 8
#define DK 32
#define BATCH 2

typedef unsigned short u16;
typedef __attribute__((ext_vector_type(8))) short short8;
typedef __attribute__((ext_vector_type(4))) float f32x4;

__device__ __forceinline__ float bf2f(u16 v) {
  union { unsigned int u; float f; } c; c.u = ((unsigned int)v) << 16; return c.f;
}
__device__ __forceinline__ float lo2f(unsigned int u) {
  union { unsigned int u; float f; } c; c.u = u << 16; return c.f;
}
__device__ __forceinline__ float hi2f(unsigned int u) {
  union { unsigned int u; float f; } c; c.u = u & 0xffff0000u; return c.f;
}
__device__ __forceinline__ u16 f2bf(float f) {
  union { unsigned int u; float f; } c; c.f = f;
  unsigned int u = c.u;
  unsigned int r = (u + 0x7FFFu + ((u >> 16) & 1u)) >> 16;
  return (u16)r;
}
// exact floor(n/48) for n in [0, 2304): magic 87382 = (2^22+32)/48
__device__ __forceinline__ int div48(int n) { return (n * 87382) >> 22; }
// fragment-order swizzle for a [rows][256] bf16 matrix
__device__ __forceinline__ int swz(int row, int k) {
  return ((row >> 4) << 12) + ((k >> 3) << 7) + ((row & 15) << 3) + (k & 7);
}

// ---------------------------------------------------------------------------
// fused prep: [0,288) transpose x -> xt (swizzled) ; [288,544) W fp32->bf16
// swizzled [q|k|v|o] ; [544,3136) Et bias table. grid 3136, block 256.
__global__ __launch_bounds__(256) void prep_kernel(
    const float* __restrict__ x,
    const float* __restrict__ Wq, const float* __restrict__ Wk,
    const float* __restrict__ Wv, const float* __restrict__ Wo,
    const float* __restrict__ lam_p,
    u16* __restrict__ xt, u16* __restrict__ Wb, u16* __restrict__ et) {
  int bid = blockIdx.x;
  int t = threadIdx.x;
  if (bid < 288) {
    int b = bid / 144, r = bid % 144;
    int c0 = (r / 36) * 64, n0 = (r % 36) * 64;
    __shared__ u16 sh[64][72];  // [n][c]
#pragma unroll
    for (int p = 0; p < 4; ++p) {
      int row = (t >> 4) + p * 16;   // c
      int col4 = (t & 15) * 4;       // n
      float4 v = *(const float4*)(x + (size_t)(b * DMODEL + c0 + row) * HW +
                                  n0 + col4);
      sh[col4 + 0][row] = f2bf(v.x);
      sh[col4 + 1][row] = f2bf(v.y);
      sh[col4 + 2][row] = f2bf(v.z);
      sh[col4 + 3][row] = f2bf(v.w);
    }
    __syncthreads();
    u16* xtb = xt + (size_t)b * HW * DMODEL;
#pragma unroll
    for (int q = 0; q < 2; ++q) {
      int nrow = t >> 2;
      int c8 = (t & 3) * 8 + q * 32;
      *(uint4*)(xtb + swz(n0 + nrow, c0 + c8)) = *(const uint4*)&sh[nrow][c8];
    }
  } else if (bid < 544) {
    int idx = (bid - 288) * 1024 + t * 4;
    int which = idx >> 16, off = idx & 65535;
    int m = off >> 8, k = off & 255;
    const float* src = (which == 0) ? Wq : (which == 1) ? Wk
                       : (which == 2) ? Wv : Wo;
    float4 v = *(const float4*)(src + off);
    ushort4 ov;
    ov.x = f2bf(v.x); ov.y = f2bf(v.y); ov.z = f2bf(v.z); ov.w = f2bf(v.w);
    *(ushort4*)(Wb + which * 65536 + swz(m, k)) = ov;
  } else {
    int id = (bid - 544) * 256 + t;
    int flat = id * 8;
    int tile = flat >> 8;
    int within = flat & 255;
    int tm = tile / 144, tq = tile - tm * 144;
    int m = tm * 16 + (within >> 4);
    int q = tq * 16 + (within & 15);
    int ym = div48(m), xm = m - ym * SW;
    int yq = div48(q), xq = q - yq * SW;
    float lam = lam_p[0];
    float dy = (float)(yq - ym);
    float dy2 = dy * dy;
    u16 o[8];
#pragma unroll
    for (int j = 0; j < 8; ++j) {
      float dx = (float)(xq + j - xm);
      o[j] = f2bf(lam * __expf(-sqrtf(dy2 + dx * dx)));
    }
    *(uint4*)(et + flat) = *(const uint4*)o;
  }
}

// ---------------------------------------------------------------------------
// QKV projection, LDS-free MFMA GEMM with swizzled frag loads (R8 structure).
// grid (36, 12, 2), block 256.
__global__ __launch_bounds__(256) void qkv_kernel(
    const u16* __restrict__ Wb, const u16* __restrict__ xt,
    const float* __restrict__ bq, const float* __restrict__ bk,
    const float* __restrict__ bv,
    u16* __restrict__ qt, u16* __restrict__ ktb, u16* __restrict__ vb) {
  int t = threadIdx.x;
  int w = t >> 6, lane = t & 63, lo = lane & 15, quad = lane >> 4;
  int n0 = blockIdx.x * 64;
  int mb = blockIdx.y, b = blockIdx.z;
  int which = mb >> 2;
  int mrel0 = (mb & 3) * 64;
  const u16* A = Wb + which * 65536 + ((mrel0 + w * 16) >> 4) * 4096 + lo * 8;
  const float* bias = (which == 0) ? bq : (which == 1) ? bk : bv;
  const u16* Bx = xt + (size_t)b * HW * DMODEL + lo * 8;

  f32x4 acc[4] = {{0.f, 0.f, 0.f, 0.f}, {0.f, 0.f, 0.f, 0.f},
                  {0.f, 0.f, 0.f, 0.f}, {0.f, 0.f, 0.f, 0.f}};
#pragma unroll
  for (int k0 = 0; k0 < DMODEL; k0 += 32) {
    int kblk = ((k0 >> 3) + quad) << 7;
    short8 af = *(const short8*)(A + kblk);
#pragma unroll
    for (int nt = 0; nt < 4; ++nt) {
      short8 bf_ = *(const short8*)(Bx + ((n0 + nt * 16) >> 4) * 4096 + kblk);
      acc[nt] = __builtin_amdgcn_mfma_f32_16x16x32_bf16(af, bf_, acc[nt], 0, 0, 0);
    }
  }

  int mbase = mrel0 + w * 16 + quad * 4;
  if (which == 2) {
#pragma unroll
    for (int reg = 0; reg < 4; ++reg) {
      int mrel = mbase + reg;
      float bi = bias[mrel];
      u16* dst = vb + (size_t)(b * DMODEL + mrel) * HW + n0 + lo;
#pragma unroll
      for (int nt = 0; nt < 4; ++nt) dst[nt * 16] = f2bf(acc[nt][reg] + bi);
    }
  } else {
    float sc = (which == 0) ? 0.17677669529663687f : 1.0f;
    int h = mbase >> 5, d0 = mbase & 31;
    u16* base = ((which == 0) ? qt : ktb) + (size_t)(b * NHEADS + h) * HW * DK;
    float bi[4], dv[4];
    bool usecos[4], usey[4];
#pragma unroll
    for (int reg = 0; reg < 4; ++reg) {
      int mrel = mbase + reg;
      bi[reg] = bias[mrel];
      int oo = mrel & 127;
      dv[reg] = expf(-0.07195578415606394f * (float)(oo & ~1));
      usecos[reg] = (oo & 1);
      usey[reg] = (mrel >= 128);
    }
#pragma unroll
    for (int nt = 0; nt < 4; ++nt) {
      int n = n0 + nt * 16 + lo;
      int yy = div48(n), xx = n - yy * SW;
      ushort4 ov;
      float vals[4];
#pragma unroll
      for (int reg = 0; reg < 4; ++reg) {
        float tv = (usey[reg] ? (float)yy : (float)xx) * dv[reg];
        float pe = usecos[reg] ? cosf(tv) : sinf(tv);
        vals[reg] = (acc[nt][reg] + bi[reg] + pe) * sc;
      }
      ov.x = f2bf(vals[0]); ov.y = f2bf(vals[1]);
      ov.z = f2bf(vals[2]); ov.w = f2bf(vals[3]);
      *(ushort4*)(base + (size_t)n * DK + d0) = ov;
    }
  }
}

// ---------------------------------------------------------------------------
// MFMA flash attention, S^T + register-resident P, split-K(4).
// K staged with permuted rows: LDS row r (within 32-chunk) holds key v where
//   rows 0-15:  v = 8*(r>>2)+(r&3)        (serves mfma instance A)
//   rows 16-31: v = 8*((r-16)>>2)+4+((r-16)&3)  (instance B)
// => C row (4*quad+reg) of instance A/B == key 8*quad+reg / 8*quad+4+reg,
// so each lane's P covers m = ks*32+quad*8+{0..7} for its own q=lo — exactly
// the PV B-operand layout. grid (36, 32, 2): y = h*4+kh. block 256.
__global__ __launch_bounds__(256) void attn_kernel(
    const u16* __restrict__ qt, const u16* __restrict__ ktb,
    const u16* __restrict__ vb, const u16* __restrict__ et,
    u16* __restrict__ po_o, float* __restrict__ po_l) {
  int t = threadIdx.x;
  int w = t >> 6;
  int lane = t & 63;
  int lo = lane & 15, quad = lane >> 4;
  int n0 = blockIdx.x * 64;
  int h = blockIdx.y >> 2, kh = blockIdx.y & 3;
  int b = blockIdx.z;

  __shared__ u16 Ks[64 * 40];  // permuted-row K tile
  __shared__ u16 Vs[32 * 72];  // V^T tile [d][m]

  const u16* qtg = qt + (size_t)(b * NHEADS + h) * HW * DK;
  const u16* ktg = ktb + (size_t)(b * NHEADS + h) * HW * DK;
  const u16* vbg = vb + (size_t)(b * DMODEL + h * DK) * HW;

  short8 qf = *(const short8*)(qtg + (size_t)(n0 + w * 16 + lo) * DK + quad * 8);

  // staging source-key for this thread's LDS row (permutation applied here)
  int srow = t >> 2;                 // LDS row 0..63
  int sks = srow >> 5, srr = srow & 31;
  int sv = (srr < 16) ? (8 * (srr >> 2) + (srr & 3))
                      : (8 * ((srr - 16) >> 2) + 4 + ((srr - 16) & 3));
  int skey = sks * 32 + sv;          // key offset within 64-tile
  int sc8 = (t & 3) * 8;

  // bias base: Et[tile = tq*144 + tm][q&15=lo, m&15 = 8*(quad&1)+j]
  int tq = (n0 >> 4) + w;
  const u16* etw = et + (size_t)tq * 144 * 256 + lo * 16 + (quad & 1) * 8;
  int qh = quad >> 1;

  f32x4 o0 = {0.f, 0.f, 0.f, 0.f}, o1 = {0.f, 0.f, 0.f, 0.f};
  float lsum = 0.f;

  for (int kt = kh * 9; kt < kh * 9 + 9; ++kt) {
    int m0 = kt * 64;
    __syncthreads();  // prev PV reads done before restaging
    {
      *(uint4*)&Ks[srow * 40 + sc8] =
          *(const uint4*)(ktg + (size_t)(m0 + skey) * DK + sc8);
      int dd = t >> 3, mo = (t & 7) * 8;
      *(uint4*)&Vs[dd * 72 + mo] =
          *(const uint4*)(vbg + (size_t)dd * HW + m0 + mo);
    }
    __syncthreads();

    // bias loads: one uint4 (8 consecutive E) per lane per 32-key chunk
    uint4 eb0 = *(const uint4*)(etw + (size_t)((m0 >> 4) + 0 + qh) * 256);
    uint4 eb1 = *(const uint4*)(etw + (size_t)((m0 >> 4) + 2 + qh) * 256);

#pragma unroll
    for (int ks = 0; ks < 2; ++ks) {
      uint4 ebv = ks ? eb1 : eb0;
      // S^T: A = permuted K rows, B = Q
      short8 kfA = *(const short8*)&Ks[(ks * 32 + lo) * 40 + quad * 8];
      short8 kfB = *(const short8*)&Ks[(ks * 32 + 16 + lo) * 40 + quad * 8];
      f32x4 z = {0.f, 0.f, 0.f, 0.f};
      f32x4 sA = __builtin_amdgcn_mfma_f32_16x16x32_bf16(kfA, qf, z, 0, 0, 0);
      f32x4 sB = __builtin_amdgcn_mfma_f32_16x16x32_bf16(kfB, qf, z, 0, 0, 0);
      // P = exp(S^T + bias): lane's m = ks*32 + 8*quad + {0..7}, q = lo
      float p0 = __expf(sA[0] + lo2f(ebv.x));
      float p1 = __expf(sA[1] + hi2f(ebv.x));
      float p2 = __expf(sA[2] + lo2f(ebv.y));
      float p3 = __expf(sA[3] + hi2f(ebv.y));
      float p4 = __expf(sB[0] + lo2f(ebv.z));
      float p5 = __expf(sB[1] + hi2f(ebv.z));
      float p6 = __expf(sB[2] + lo2f(ebv.w));
      float p7 = __expf(sB[3] + hi2f(ebv.w));
      lsum += ((p0 + p1) + (p2 + p3)) + ((p4 + p5) + (p6 + p7));
      // pack into PV B-fragment (k = quad*8 + j), all in-lane
      u16 pk[8] = {f2bf(p0), f2bf(p1), f2bf(p2), f2bf(p3),
                   f2bf(p4), f2bf(p5), f2bf(p6), f2bf(p7)};
      short8 pfrag = *(const short8*)pk;
      // O^T += V^T P^T : A = V^T rows d, B = P (q cols)
      short8 v0 = *(const short8*)&Vs[lo * 72 + ks * 32 + quad * 8];
      o0 = __builtin_amdgcn_mfma_f32_16x16x32_bf16(v0, pfrag, o0, 0, 0, 0);
      short8 v1 = *(const short8*)&Vs[(16 + lo) * 72 + ks * 32 + quad * 8];
      o1 = __builtin_amdgcn_mfma_f32_16x16x32_bf16(v1, pfrag, o1, 0, 0, 0);
    }
  }

  // full rowsum for q = lo: reduce across the 4 quads
  lsum += __shfl_xor(lsum, 16);
  lsum += __shfl_xor(lsum, 32);

  // store partials: o0[reg] = O^T[d=4*quad+reg][q=w*16+lo], o1: d+16
  int slot = (b * NHEADS + h) * 36 + blockIdx.x;
  u16* pw = po_o + (size_t)(kh * 576 + slot) * 2048 + w * 512;  // u16 units
  ushort4 s0, s1;
  s0.x = f2bf(o0[0]); s0.y = f2bf(o0[1]); s0.z = f2bf(o0[2]); s0.w = f2bf(o0[3]);
  s1.x = f2bf(o1[0]); s1.y = f2bf(o1[1]); s1.z = f2bf(o1[2]); s1.w = f2bf(o1[3]);
  *(ushort4*)(pw + lane * 4) = s0;
  *(ushort4*)(pw + 256 + lane * 4) = s1;
  if (quad == 0)
    po_l[(size_t)(kh * 576 + slot) * 64 + w * 16 + lo] = lsum;
}

// ---------------------------------------------------------------------------
// reduce: sum the four split-K partials, normalize, write aot (swizzled).
// Partial semantic: element (lane, reg, half) = O^T[d=4*quad+reg+16*half][q=w*16+lo].
// grid (36, 8, 2), block 256.
__global__ __launch_bounds__(256) void reduce_kernel(
    const u16* __restrict__ po_o, const float* __restrict__ po_l,
    u16* __restrict__ aot) {
  int t = threadIdx.x;
  int w = t >> 6, lane = t & 63, lo = lane & 15, quad = lane >> 4;
  int qt_ = blockIdx.x, h = blockIdx.y, b = blockIdx.z;
  int slot = (b * NHEADS + h) * 36 + qt_;

  float s0[4] = {0.f, 0.f, 0.f, 0.f}, s1[4] = {0.f, 0.f, 0.f, 0.f};
  float lt = 0.f;
#pragma unroll
  for (int kh = 0; kh < 4; ++kh) {
    const u16* p = po_o + (size_t)(kh * 576 + slot) * 2048 + w * 512;
    ushort4 a0 = *(const ushort4*)(p + lane * 4);
    ushort4 a1 = *(const ushort4*)(p + 256 + lane * 4);
    s0[0] += bf2f(a0.x); s0[1] += bf2f(a0.y);
    s0[2] += bf2f(a0.z); s0[3] += bf2f(a0.w);
    s1[0] += bf2f(a1.x); s1[1] += bf2f(a1.y);
    s1[2] += bf2f(a1.z); s1[3] += bf2f(a1.w);
    lt += po_l[(size_t)(kh * 576 + slot) * 64 + w * 16 + lo];
  }
  float inv = 1.0f / lt;

  int n = qt_ * 64 + w * 16 + lo;
  u16* aog = aot + (size_t)b * HW * DMODEL;
  ushort4 w0, w1;
  w0.x = f2bf(s0[0] * inv); w0.y = f2bf(s0[1] * inv);
  w0.z = f2bf(s0[2] * inv); w0.w = f2bf(s0[3] * inv);
  w1.x = f2bf(s1[0] * inv); w1.y = f2bf(s1[1] * inv);
  w1.z = f2bf(s1[2] * inv); w1.w = f2bf(s1[3] * inv);
  *(ushort4*)&aog[swz(n, h * DK + quad * 4)] = w0;
  *(ushort4*)&aog[swz(n, h * DK + 16 + quad * 4)] = w1;
}

// ---------------------------------------------------------------------------
// out[b][c][n] = x + gamma * (Wo ao)[c][n] + bo[c], LDS-free MFMA GEMM with
// swizzled frag loads. grid (36, 4, 2), block 256.
__global__ __launch_bounds__(256) void out_kernel(
    const float* __restrict__ x, const u16* __restrict__ Wob,
    const float* __restrict__ bo, const float* __restrict__ gp,
    const u16* __restrict__ aot, float* __restrict__ out) {
  int t = threadIdx.x;
  int w = t >> 6, lane = t & 63, lo = lane & 15, quad = lane >> 4;
  int n0 = blockIdx.x * 64;
  int c0 = blockIdx.y * 64;
  int b = blockIdx.z;
  float gamma = gp[0];
  const u16* A = Wob + ((c0 + w * 16) >> 4) * 4096 + lo * 8;
  const u16* Ba = aot + (size_t)b * HW * DMODEL + lo * 8;

  f32x4 acc[4] = {{0.f, 0.f, 0.f, 0.f}, {0.f, 0.f, 0.f, 0.f},
                  {0.f, 0.f, 0.f, 0.f}, {0.f, 0.f, 0.f, 0.f}};
#pragma unroll
  for (int k0 = 0; k0 < DMODEL; k0 += 32) {
    int kblk = ((k0 >> 3) + quad) << 7;
    short8 af = *(const short8*)(A + kblk);
#pragma unroll
    for (int nt = 0; nt < 4; ++nt) {
      short8 bf_ = *(const short8*)(Ba + ((n0 + nt * 16) >> 4) * 4096 + kblk);
      acc[nt] = __builtin_amdgcn_mfma_f32_16x16x32_bf16(af, bf_, acc[nt], 0, 0, 0);
    }
  }

#pragma unroll
  for (int reg = 0; reg < 4; ++reg) {
    int c = c0 + w * 16 + quad * 4 + reg;
    float bi = bo[c];
    const float* xs = x + (size_t)(b * DMODEL + c) * HW + n0 + lo;
    float* os = out + (size_t)(b * DMODEL + c) * HW + n0 + lo;
#pragma unroll
    for (int nt = 0; nt < 4; ++nt)
      os[nt * 16] = xs[nt * 16] + gamma * acc[nt][reg] + bi;
  }
}

// ---------------------------------------------------------------------------
extern "C" void kernel_launch(void* const* d_in, const int* in_sizes, int n_in,
                              void* d_out, int out_size, void* d_ws,
                              size_t ws_size, hipStream_t stream) {
  const float* x   = (const float*)d_in[0];
  const float* Wq  = (const float*)d_in[1];
  const float* bq  = (const float*)d_in[2];
  const float* Wk  = (const float*)d_in[3];
  const float* bk  = (const float*)d_in[4];
  const float* Wv  = (const float*)d_in[5];
  const float* bv  = (const float*)d_in[6];
  const float* Wo  = (const float*)d_in[7];
  const float* bo  = (const float*)d_in[8];
  const float* lam = (const float*)d_in[9];
  const float* gam = (const float*)d_in[10];

  // ws layout (bytes); ws_size ~268 MB (R11 fill-dispatch evidence):
  //   (unused)   [0, 36864)
  //   Wb    bf16 [36864, 561152)      4*65536*2, [q|k|v|o], swizzled
  //   xt    bf16 [561152, 2920448)    swizzled; ALIASED with aot
  //   qt    bf16 [2920448, 5279744)
  //   ktb   bf16 [5279744, 7639040)
  //   vb    bf16 [7639040, 9998336)
  //   et    bf16 [9998336, 20615168)  2304*2304 bias, fragment-tile order
  //   po_o  bf16 [20615168, 30052352) split-K(4) partial O
  //   po_l  f32  [30052352, 30642176) split-K(4) partial rowsums
  char* wsb = (char*)d_ws;
  u16* Wb  = (u16*)(wsb + 36864);
  u16* xt  = (u16*)(wsb + 561152);
  u16* aot = xt;  // alias, sequential lifetime
  u16* qt  = (u16*)(wsb + 2920448);
  u16* ktb = (u16*)(wsb + 5279744);
  u16* vb  = (u16*)(wsb + 7639040);
  u16* et  = (u16*)(wsb + 9998336);
  u16* po_o = (u16*)(wsb + 20615168);
  float* po_l = (float*)(wsb + 30052352);
  float* out = (float*)d_out;

  prep_kernel<<<dim3(3136), 256, 0, stream>>>(x, Wq, Wk, Wv, Wo, lam,
                                              xt, Wb, et);
  qkv_kernel<<<dim3(36, 12, BATCH), 256, 0, stream>>>(Wb, xt, bq, bk, bv,
                                                      qt, ktb, vb);
  attn_kernel<<<dim3(36, 32, BATCH), 256, 0, stream>>>(qt, ktb, vb, et,
                                                       po_o, po_l);
  reduce_kernel<<<dim3(36, 8, BATCH), 256, 0, stream>>>(po_o, po_l, aot);
  out_kernel<<<dim3(36, 4, BATCH), 256, 0, stream>>>(x, Wb + 3 * 65536, bo, gam,
                                                     aot, out);
}

// Round 14
// 131.274 us; speedup vs baseline: 1.4400x; 1.0263x over previous
//
#include <hip/hip_runtime.h>

// Problem constants (B=2, C=256, H=W=48, d_model=256, 8 heads, d_k=32)
// Inputs/outputs fp32. Internals bf16; all matmuls + attention on MFMA.
// Wb / xt / aot in MFMA-fragment-order swizzle:
//   addr(row,k) = (row>>4)*4096 + (k>>3)*128 + (row&15)*8 + (k&7)
// Distance bias in fragment-tile order: Et[T1*144+T2][(i1)*16+i2].
// attn: S^T orientation + register-resident P (R13) + DOUBLE-BUFFERED K/V
// staging: one barrier per key-tile instead of two; staging latency hidden
// under compute. 4-way split-K (fixed-max softmax => partials additive).
#define HW 2304
#define SW 48
#define DMODEL 256
#define NHEADS 8
#define DK 32
#define BATCH 2

typedef unsigned short u16;
typedef __attribute__((ext_vector_type(8))) short short8;
typedef __attribute__((ext_vector_type(4))) float f32x4;

__device__ __forceinline__ float bf2f(u16 v) {
  union { unsigned int u; float f; } c; c.u = ((unsigned int)v) << 16; return c.f;
}
__device__ __forceinline__ float lo2f(unsigned int u) {
  union { unsigned int u; float f; } c; c.u = u << 16; return c.f;
}
__device__ __forceinline__ float hi2f(unsigned int u) {
  union { unsigned int u; float f; } c; c.u = u & 0xffff0000u; return c.f;
}
__device__ __forceinline__ u16 f2bf(float f) {
  union { unsigned int u; float f; } c; c.f = f;
  unsigned int u = c.u;
  unsigned int r = (u + 0x7FFFu + ((u >> 16) & 1u)) >> 16;
  return (u16)r;
}
// exact floor(n/48) for n in [0, 2304): magic 87382 = (2^22+32)/48
__device__ __forceinline__ int div48(int n) { return (n * 87382) >> 22; }
// fragment-order swizzle for a [rows][256] bf16 matrix
__device__ __forceinline__ int swz(int row, int k) {
  return ((row >> 4) << 12) + ((k >> 3) << 7) + ((row & 15) << 3) + (k & 7);
}

// ---------------------------------------------------------------------------
// fused prep: [0,288) transpose x -> xt (swizzled) ; [288,544) W fp32->bf16
// swizzled [q|k|v|o] ; [544,3136) Et bias table. grid 3136, block 256.
__global__ __launch_bounds__(256) void prep_kernel(
    const float* __restrict__ x,
    const float* __restrict__ Wq, const float* __restrict__ Wk,
    const float* __restrict__ Wv, const float* __restrict__ Wo,
    const float* __restrict__ lam_p,
    u16* __restrict__ xt, u16* __restrict__ Wb, u16* __restrict__ et) {
  int bid = blockIdx.x;
  int t = threadIdx.x;
  if (bid < 288) {
    int b = bid / 144, r = bid % 144;
    int c0 = (r / 36) * 64, n0 = (r % 36) * 64;
    __shared__ u16 sh[64][72];  // [n][c]
#pragma unroll
    for (int p = 0; p < 4; ++p) {
      int row = (t >> 4) + p * 16;   // c
      int col4 = (t & 15) * 4;       // n
      float4 v = *(const float4*)(x + (size_t)(b * DMODEL + c0 + row) * HW +
                                  n0 + col4);
      sh[col4 + 0][row] = f2bf(v.x);
      sh[col4 + 1][row] = f2bf(v.y);
      sh[col4 + 2][row] = f2bf(v.z);
      sh[col4 + 3][row] = f2bf(v.w);
    }
    __syncthreads();
    u16* xtb = xt + (size_t)b * HW * DMODEL;
#pragma unroll
    for (int q = 0; q < 2; ++q) {
      int nrow = t >> 2;
      int c8 = (t & 3) * 8 + q * 32;
      *(uint4*)(xtb + swz(n0 + nrow, c0 + c8)) = *(const uint4*)&sh[nrow][c8];
    }
  } else if (bid < 544) {
    int idx = (bid - 288) * 1024 + t * 4;
    int which = idx >> 16, off = idx & 65535;
    int m = off >> 8, k = off & 255;
    const float* src = (which == 0) ? Wq : (which == 1) ? Wk
                       : (which == 2) ? Wv : Wo;
    float4 v = *(const float4*)(src + off);
    ushort4 ov;
    ov.x = f2bf(v.x); ov.y = f2bf(v.y); ov.z = f2bf(v.z); ov.w = f2bf(v.w);
    *(ushort4*)(Wb + which * 65536 + swz(m, k)) = ov;
  } else {
    int id = (bid - 544) * 256 + t;
    int flat = id * 8;
    int tile = flat >> 8;
    int within = flat & 255;
    int tm = tile / 144, tq = tile - tm * 144;
    int m = tm * 16 + (within >> 4);
    int q = tq * 16 + (within & 15);
    int ym = div48(m), xm = m - ym * SW;
    int yq = div48(q), xq = q - yq * SW;
    float lam = lam_p[0];
    float dy = (float)(yq - ym);
    float dy2 = dy * dy;
    u16 o[8];
#pragma unroll
    for (int j = 0; j < 8; ++j) {
      float dx = (float)(xq + j - xm);
      o[j] = f2bf(lam * __expf(-sqrtf(dy2 + dx * dx)));
    }
    *(uint4*)(et + flat) = *(const uint4*)o;
  }
}

// ---------------------------------------------------------------------------
// QKV projection, LDS-free MFMA GEMM with swizzled frag loads (R8 structure).
// grid (36, 12, 2), block 256.
__global__ __launch_bounds__(256) void qkv_kernel(
    const u16* __restrict__ Wb, const u16* __restrict__ xt,
    const float* __restrict__ bq, const float* __restrict__ bk,
    const float* __restrict__ bv,
    u16* __restrict__ qt, u16* __restrict__ ktb, u16* __restrict__ vb) {
  int t = threadIdx.x;
  int w = t >> 6, lane = t & 63, lo = lane & 15, quad = lane >> 4;
  int n0 = blockIdx.x * 64;
  int mb = blockIdx.y, b = blockIdx.z;
  int which = mb >> 2;
  int mrel0 = (mb & 3) * 64;
  const u16* A = Wb + which * 65536 + ((mrel0 + w * 16) >> 4) * 4096 + lo * 8;
  const float* bias = (which == 0) ? bq : (which == 1) ? bk : bv;
  const u16* Bx = xt + (size_t)b * HW * DMODEL + lo * 8;

  f32x4 acc[4] = {{0.f, 0.f, 0.f, 0.f}, {0.f, 0.f, 0.f, 0.f},
                  {0.f, 0.f, 0.f, 0.f}, {0.f, 0.f, 0.f, 0.f}};
#pragma unroll
  for (int k0 = 0; k0 < DMODEL; k0 += 32) {
    int kblk = ((k0 >> 3) + quad) << 7;
    short8 af = *(const short8*)(A + kblk);
#pragma unroll
    for (int nt = 0; nt < 4; ++nt) {
      short8 bf_ = *(const short8*)(Bx + ((n0 + nt * 16) >> 4) * 4096 + kblk);
      acc[nt] = __builtin_amdgcn_mfma_f32_16x16x32_bf16(af, bf_, acc[nt], 0, 0, 0);
    }
  }

  int mbase = mrel0 + w * 16 + quad * 4;
  if (which == 2) {
#pragma unroll
    for (int reg = 0; reg < 4; ++reg) {
      int mrel = mbase + reg;
      float bi = bias[mrel];
      u16* dst = vb + (size_t)(b * DMODEL + mrel) * HW + n0 + lo;
#pragma unroll
      for (int nt = 0; nt < 4; ++nt) dst[nt * 16] = f2bf(acc[nt][reg] + bi);
    }
  } else {
    float sc = (which == 0) ? 0.17677669529663687f : 1.0f;
    int h = mbase >> 5, d0 = mbase & 31;
    u16* base = ((which == 0) ? qt : ktb) + (size_t)(b * NHEADS + h) * HW * DK;
    float bi[4], dv[4];
    bool usecos[4], usey[4];
#pragma unroll
    for (int reg = 0; reg < 4; ++reg) {
      int mrel = mbase + reg;
      bi[reg] = bias[mrel];
      int oo = mrel & 127;
      dv[reg] = expf(-0.07195578415606394f * (float)(oo & ~1));
      usecos[reg] = (oo & 1);
      usey[reg] = (mrel >= 128);
    }
#pragma unroll
    for (int nt = 0; nt < 4; ++nt) {
      int n = n0 + nt * 16 + lo;
      int yy = div48(n), xx = n - yy * SW;
      ushort4 ov;
      float vals[4];
#pragma unroll
      for (int reg = 0; reg < 4; ++reg) {
        float tv = (usey[reg] ? (float)yy : (float)xx) * dv[reg];
        float pe = usecos[reg] ? cosf(tv) : sinf(tv);
        vals[reg] = (acc[nt][reg] + bi[reg] + pe) * sc;
      }
      ov.x = f2bf(vals[0]); ov.y = f2bf(vals[1]);
      ov.z = f2bf(vals[2]); ov.w = f2bf(vals[3]);
      *(ushort4*)(base + (size_t)n * DK + d0) = ov;
    }
  }
}

// ---------------------------------------------------------------------------
// MFMA flash attention, S^T + register-resident P, split-K(4), DOUBLE-BUFFERED
// K/V staging (ping-pong, one barrier per tile). K staged with permuted rows
// (see R13 derivation): C row (4*quad+reg) of instance A/B == key 8*quad+reg /
// 8*quad+4+reg, so each lane's P is exactly the PV B-operand fragment.
// grid (36, 32, 2): y = h*4+kh. block 256.
__global__ __launch_bounds__(256) void attn_kernel(
    const u16* __restrict__ qt, const u16* __restrict__ ktb,
    const u16* __restrict__ vb, const u16* __restrict__ et,
    u16* __restrict__ po_o, float* __restrict__ po_l) {
  int t = threadIdx.x;
  int w = t >> 6;
  int lane = t & 63;
  int lo = lane & 15, quad = lane >> 4;
  int n0 = blockIdx.x * 64;
  int h = blockIdx.y >> 2, kh = blockIdx.y & 3;
  int b = blockIdx.z;

  __shared__ u16 Ks[2][64 * 40];  // ping-pong permuted-row K tiles
  __shared__ u16 Vs[2][32 * 72];  // ping-pong V^T tiles [d][m]

  const u16* qtg = qt + (size_t)(b * NHEADS + h) * HW * DK;
  const u16* ktg = ktb + (size_t)(b * NHEADS + h) * HW * DK;
  const u16* vbg = vb + (size_t)(b * DMODEL + h * DK) * HW;

  short8 qf = *(const short8*)(qtg + (size_t)(n0 + w * 16 + lo) * DK + quad * 8);

  // staging source-key for this thread's LDS row (permutation applied here)
  int srow = t >> 2;                 // LDS row 0..63
  int sks = srow >> 5, srr = srow & 31;
  int sv = (srr < 16) ? (8 * (srr >> 2) + (srr & 3))
                      : (8 * ((srr - 16) >> 2) + 4 + ((srr - 16) & 3));
  int skey = sks * 32 + sv;          // key offset within 64-tile
  int sc8 = (t & 3) * 8;
  int vdd = t >> 3, vmo = (t & 7) * 8;

  // bias base: Et[tile = tq*144 + tm][q&15=lo, m&15 = 8*(quad&1)+j]
  int tq = (n0 >> 4) + w;
  const u16* etw = et + (size_t)tq * 144 * 256 + lo * 16 + (quad & 1) * 8;
  int qh = quad >> 1;

  f32x4 o0 = {0.f, 0.f, 0.f, 0.f}, o1 = {0.f, 0.f, 0.f, 0.f};
  float lsum = 0.f;

  const int kt0 = kh * 9;
  // prologue: stage tile kt0 into buffer 0
  {
    int m0 = kt0 * 64;
    *(uint4*)&Ks[0][srow * 40 + sc8] =
        *(const uint4*)(ktg + (size_t)(m0 + skey) * DK + sc8);
    *(uint4*)&Vs[0][vdd * 72 + vmo] =
        *(const uint4*)(vbg + (size_t)vdd * HW + m0 + vmo);
  }
  __syncthreads();

  for (int i = 0; i < 9; ++i) {
    int cur = i & 1;
    // stage tile i+1 into the other buffer (no barrier needed: distinct buf)
    if (i + 1 < 9) {
      int m1 = (kt0 + i + 1) * 64;
      *(uint4*)&Ks[cur ^ 1][srow * 40 + sc8] =
          *(const uint4*)(ktg + (size_t)(m1 + skey) * DK + sc8);
      *(uint4*)&Vs[cur ^ 1][vdd * 72 + vmo] =
          *(const uint4*)(vbg + (size_t)vdd * HW + m1 + vmo);
    }

    int m0 = (kt0 + i) * 64;
    // bias loads: one uint4 (8 consecutive E) per lane per 32-key chunk
    uint4 eb0 = *(const uint4*)(etw + (size_t)((m0 >> 4) + 0 + qh) * 256);
    uint4 eb1 = *(const uint4*)(etw + (size_t)((m0 >> 4) + 2 + qh) * 256);

#pragma unroll
    for (int ks = 0; ks < 2; ++ks) {
      uint4 ebv = ks ? eb1 : eb0;
      // S^T: A = permuted K rows, B = Q
      short8 kfA = *(const short8*)&Ks[cur][(ks * 32 + lo) * 40 + quad * 8];
      short8 kfB = *(const short8*)&Ks[cur][(ks * 32 + 16 + lo) * 40 + quad * 8];
      f32x4 z = {0.f, 0.f, 0.f, 0.f};
      f32x4 sA = __builtin_amdgcn_mfma_f32_16x16x32_bf16(kfA, qf, z, 0, 0, 0);
      f32x4 sB = __builtin_amdgcn_mfma_f32_16x16x32_bf16(kfB, qf, z, 0, 0, 0);
      // P = exp(S^T + bias): lane's m = ks*32 + 8*quad + {0..7}, q = lo
      float p0 = __expf(sA[0] + lo2f(ebv.x));
      float p1 = __expf(sA[1] + hi2f(ebv.x));
      float p2 = __expf(sA[2] + lo2f(ebv.y));
      float p3 = __expf(sA[3] + hi2f(ebv.y));
      float p4 = __expf(sB[0] + lo2f(ebv.z));
      float p5 = __expf(sB[1] + hi2f(ebv.z));
      float p6 = __expf(sB[2] + lo2f(ebv.w));
      float p7 = __expf(sB[3] + hi2f(ebv.w));
      lsum += ((p0 + p1) + (p2 + p3)) + ((p4 + p5) + (p6 + p7));
      // pack into PV B-fragment (k = quad*8 + j), all in-lane
      u16 pk[8] = {f2bf(p0), f2bf(p1), f2bf(p2), f2bf(p3),
                   f2bf(p4), f2bf(p5), f2bf(p6), f2bf(p7)};
      short8 pfrag = *(const short8*)pk;
      // O^T += V^T P^T : A = V^T rows d, B = P (q cols)
      short8 v0 = *(const short8*)&Vs[cur][lo * 72 + ks * 32 + quad * 8];
      o0 = __builtin_amdgcn_mfma_f32_16x16x32_bf16(v0, pfrag, o0, 0, 0, 0);
      short8 v1 = *(const short8*)&Vs[cur][(16 + lo) * 72 + ks * 32 + quad * 8];
      o1 = __builtin_amdgcn_mfma_f32_16x16x32_bf16(v1, pfrag, o1, 0, 0, 0);
    }
    // single barrier: staging of i+1 complete AND compute reads of buf cur
    // done before it is overwritten at iteration i+2
    __syncthreads();
  }

  // full rowsum for q = lo: reduce across the 4 quads
  lsum += __shfl_xor(lsum, 16);
  lsum += __shfl_xor(lsum, 32);

  // store partials: o0[reg] = O^T[d=4*quad+reg][q=w*16+lo], o1: d+16
  int slot = (b * NHEADS + h) * 36 + blockIdx.x;
  u16* pw = po_o + (size_t)(kh * 576 + slot) * 2048 + w * 512;  // u16 units
  ushort4 s0, s1;
  s0.x = f2bf(o0[0]); s0.y = f2bf(o0[1]); s0.z = f2bf(o0[2]); s0.w = f2bf(o0[3]);
  s1.x = f2bf(o1[0]); s1.y = f2bf(o1[1]); s1.z = f2bf(o1[2]); s1.w = f2bf(o1[3]);
  *(ushort4*)(pw + lane * 4) = s0;
  *(ushort4*)(pw + 256 + lane * 4) = s1;
  if (quad == 0)
    po_l[(size_t)(kh * 576 + slot) * 64 + w * 16 + lo] = lsum;
}

// ---------------------------------------------------------------------------
// reduce: sum the four split-K partials, normalize, write aot (swizzled).
// Partial semantic: element (lane, reg, half) = O^T[d=4*quad+reg+16*half][q=w*16+lo].
// grid (36, 8, 2), block 256.
__global__ __launch_bounds__(256) void reduce_kernel(
    const u16* __restrict__ po_o, const float* __restrict__ po_l,
    u16* __restrict__ aot) {
  int t = threadIdx.x;
  int w = t >> 6, lane = t & 63, lo = lane & 15, quad = lane >> 4;
  int qt_ = blockIdx.x, h = blockIdx.y, b = blockIdx.z;
  int slot = (b * NHEADS + h) * 36 + qt_;

  float s0[4] = {0.f, 0.f, 0.f, 0.f}, s1[4] = {0.f, 0.f, 0.f, 0.f};
  float lt = 0.f;
#pragma unroll
  for (int kh = 0; kh < 4; ++kh) {
    const u16* p = po_o + (size_t)(kh * 576 + slot) * 2048 + w * 512;
    ushort4 a0 = *(const ushort4*)(p + lane * 4);
    ushort4 a1 = *(const ushort4*)(p + 256 + lane * 4);
    s0[0] += bf2f(a0.x); s0[1] += bf2f(a0.y);
    s0[2] += bf2f(a0.z); s0[3] += bf2f(a0.w);
    s1[0] += bf2f(a1.x); s1[1] += bf2f(a1.y);
    s1[2] += bf2f(a1.z); s1[3] += bf2f(a1.w);
    lt += po_l[(size_t)(kh * 576 + slot) * 64 + w * 16 + lo];
  }
  float inv = 1.0f / lt;

  int n = qt_ * 64 + w * 16 + lo;
  u16* aog = aot + (size_t)b * HW * DMODEL;
  ushort4 w0, w1;
  w0.x = f2bf(s0[0] * inv); w0.y = f2bf(s0[1] * inv);
  w0.z = f2bf(s0[2] * inv); w0.w = f2bf(s0[3] * inv);
  w1.x = f2bf(s1[0] * inv); w1.y = f2bf(s1[1] * inv);
  w1.z = f2bf(s1[2] * inv); w1.w = f2bf(s1[3] * inv);
  *(ushort4*)&aog[swz(n, h * DK + quad * 4)] = w0;
  *(ushort4*)&aog[swz(n, h * DK + 16 + quad * 4)] = w1;
}

// ---------------------------------------------------------------------------
// out[b][c][n] = x + gamma * (Wo ao)[c][n] + bo[c], LDS-free MFMA GEMM with
// swizzled frag loads. grid (36, 4, 2), block 256.
__global__ __launch_bounds__(256) void out_kernel(
    const float* __restrict__ x, const u16* __restrict__ Wob,
    const float* __restrict__ bo, const float* __restrict__ gp,
    const u16* __restrict__ aot, float* __restrict__ out) {
  int t = threadIdx.x;
  int w = t >> 6, lane = t & 63, lo = lane & 15, quad = lane >> 4;
  int n0 = blockIdx.x * 64;
  int c0 = blockIdx.y * 64;
  int b = blockIdx.z;
  float gamma = gp[0];
  const u16* A = Wob + ((c0 + w * 16) >> 4) * 4096 + lo * 8;
  const u16* Ba = aot + (size_t)b * HW * DMODEL + lo * 8;

  f32x4 acc[4] = {{0.f, 0.f, 0.f, 0.f}, {0.f, 0.f, 0.f, 0.f},
                  {0.f, 0.f, 0.f, 0.f}, {0.f, 0.f, 0.f, 0.f}};
#pragma unroll
  for (int k0 = 0; k0 < DMODEL; k0 += 32) {
    int kblk = ((k0 >> 3) + quad) << 7;
    short8 af = *(const short8*)(A + kblk);
#pragma unroll
    for (int nt = 0; nt < 4; ++nt) {
      short8 bf_ = *(const short8*)(Ba + ((n0 + nt * 16) >> 4) * 4096 + kblk);
      acc[nt] = __builtin_amdgcn_mfma_f32_16x16x32_bf16(af, bf_, acc[nt], 0, 0, 0);
    }
  }

#pragma unroll
  for (int reg = 0; reg < 4; ++reg) {
    int c = c0 + w * 16 + quad * 4 + reg;
    float bi = bo[c];
    const float* xs = x + (size_t)(b * DMODEL + c) * HW + n0 + lo;
    float* os = out + (size_t)(b * DMODEL + c) * HW + n0 + lo;
#pragma unroll
    for (int nt = 0; nt < 4; ++nt)
      os[nt * 16] = xs[nt * 16] + gamma * acc[nt][reg] + bi;
  }
}

// ---------------------------------------------------------------------------
extern "C" void kernel_launch(void* const* d_in, const int* in_sizes, int n_in,
                              void* d_out, int out_size, void* d_ws,
                              size_t ws_size, hipStream_t stream) {
  const float* x   = (const float*)d_in[0];
  const float* Wq  = (const float*)d_in[1];
  const float* bq  = (const float*)d_in[2];
  const float* Wk  = (const float*)d_in[3];
  const float* bk  = (const float*)d_in[4];
  const float* Wv  = (const float*)d_in[5];
  const float* bv  = (const float*)d_in[6];
  const float* Wo  = (const float*)d_in[7];
  const float* bo  = (const float*)d_in[8];
  const float* lam = (const float*)d_in[9];
  const float* gam = (const float*)d_in[10];

  // ws layout (bytes); ws_size ~268 MB (R11 fill-dispatch evidence):
  //   (unused)   [0, 36864)
  //   Wb    bf16 [36864, 561152)      4*65536*2, [q|k|v|o], swizzled
  //   xt    bf16 [561152, 2920448)    swizzled; ALIASED with aot
  //   qt    bf16 [2920448, 5279744)
  //   ktb   bf16 [5279744, 7639040)
  //   vb    bf16 [7639040, 9998336)
  //   et    bf16 [9998336, 20615168)  2304*2304 bias, fragment-tile order
  //   po_o  bf16 [20615168, 30052352) split-K(4) partial O
  //   po_l  f32  [30052352, 30642176) split-K(4) partial rowsums
  char* wsb = (char*)d_ws;
  u16* Wb  = (u16*)(wsb + 36864);
  u16* xt  = (u16*)(wsb + 561152);
  u16* aot = xt;  // alias, sequential lifetime
  u16* qt  = (u16*)(wsb + 2920448);
  u16* ktb = (u16*)(wsb + 5279744);
  u16* vb  = (u16*)(wsb + 7639040);
  u16* et  = (u16*)(wsb + 9998336);
  u16* po_o = (u16*)(wsb + 20615168);
  float* po_l = (float*)(wsb + 30052352);
  float* out = (float*)d_out;

  prep_kernel<<<dim3(3136), 256, 0, stream>>>(x, Wq, Wk, Wv, Wo, lam,
                                              xt, Wb, et);
  qkv_kernel<<<dim3(36, 12, BATCH), 256, 0, stream>>>(Wb, xt, bq, bk, bv,
                                                      qt, ktb, vb);
  attn_kernel<<<dim3(36, 32, BATCH), 256, 0, stream>>>(qt, ktb, vb, et,
                                                       po_o, po_l);
  reduce_kernel<<<dim3(36, 8, BATCH), 256, 0, stream>>>(po_o, po_l, aot);
  out_kernel<<<dim3(36, 4, BATCH), 256, 0, stream>>>(x, Wb + 3 * 65536, bo, gam,
                                                     aot, out);
}

// Round 15
// 129.054 us; speedup vs baseline: 1.4648x; 1.0172x over previous
//
#include <hip/hip_runtime.h>

// Problem constants (B=2, C=256, H=W=48, d_model=256, 8 heads, d_k=32)
// Inputs/outputs fp32. Internals bf16; all matmuls + attention on MFMA.
// Wb / xt / aot in MFMA-fragment-order swizzle:
//   addr(row,k) = (row>>4)*4096 + (k>>3)*128 + (row&15)*8 + (k&7)
// Distance bias in fragment-tile order: Et[T1*144+T2][(i1)*16+i2].
// attn: S^T + register-resident P + double-buffered K/V staging + split-K(4).
// R15: P/partial-O bf16 packing via v_perm truncation (1 op per 2 values).
#define HW 2304
#define SW 48
#define DMODEL 256
#define NHEADS 8
#define DK 32
#define BATCH 2

typedef unsigned short u16;
typedef __attribute__((ext_vector_type(8))) short short8;
typedef __attribute__((ext_vector_type(4))) float f32x4;

__device__ __forceinline__ float bf2f(u16 v) {
  union { unsigned int u; float f; } c; c.u = ((unsigned int)v) << 16; return c.f;
}
__device__ __forceinline__ float lo2f(unsigned int u) {
  union { unsigned int u; float f; } c; c.u = u << 16; return c.f;
}
__device__ __forceinline__ float hi2f(unsigned int u) {
  union { unsigned int u; float f; } c; c.u = u & 0xffff0000u; return c.f;
}
__device__ __forceinline__ u16 f2bf(float f) {
  union { unsigned int u; float f; } c; c.f = f;
  unsigned int u = c.u;
  unsigned int r = (u + 0x7FFFu + ((u >> 16) & 1u)) >> 16;
  return (u16)r;
}
// pack two floats -> two bf16 (TRUNCATION) in one v_perm_b32:
// result lo16 = a.hi16, hi16 = b.hi16
__device__ __forceinline__ unsigned int pkbf(float a, float b) {
  union { float f; unsigned int u; } ca, cb;
  ca.f = a; cb.f = b;
  return __builtin_amdgcn_perm(ca.u, cb.u, 0x03020706u);
}
// exact floor(n/48) for n in [0, 2304): magic 87382 = (2^22+32)/48
__device__ __forceinline__ int div48(int n) { return (n * 87382) >> 22; }
// fragment-order swizzle for a [rows][256] bf16 matrix
__device__ __forceinline__ int swz(int row, int k) {
  return ((row >> 4) << 12) + ((k >> 3) << 7) + ((row & 15) << 3) + (k & 7);
}

// ---------------------------------------------------------------------------
// fused prep: [0,288) transpose x -> xt (swizzled) ; [288,544) W fp32->bf16
// swizzled [q|k|v|o] ; [544,3136) Et bias table. grid 3136, block 256.
__global__ __launch_bounds__(256) void prep_kernel(
    const float* __restrict__ x,
    const float* __restrict__ Wq, const float* __restrict__ Wk,
    const float* __restrict__ Wv, const float* __restrict__ Wo,
    const float* __restrict__ lam_p,
    u16* __restrict__ xt, u16* __restrict__ Wb, u16* __restrict__ et) {
  int bid = blockIdx.x;
  int t = threadIdx.x;
  if (bid < 288) {
    int b = bid / 144, r = bid % 144;
    int c0 = (r / 36) * 64, n0 = (r % 36) * 64;
    __shared__ u16 sh[64][72];  // [n][c]
#pragma unroll
    for (int p = 0; p < 4; ++p) {
      int row = (t >> 4) + p * 16;   // c
      int col4 = (t & 15) * 4;       // n
      float4 v = *(const float4*)(x + (size_t)(b * DMODEL + c0 + row) * HW +
                                  n0 + col4);
      sh[col4 + 0][row] = f2bf(v.x);
      sh[col4 + 1][row] = f2bf(v.y);
      sh[col4 + 2][row] = f2bf(v.z);
      sh[col4 + 3][row] = f2bf(v.w);
    }
    __syncthreads();
    u16* xtb = xt + (size_t)b * HW * DMODEL;
#pragma unroll
    for (int q = 0; q < 2; ++q) {
      int nrow = t >> 2;
      int c8 = (t & 3) * 8 + q * 32;
      *(uint4*)(xtb + swz(n0 + nrow, c0 + c8)) = *(const uint4*)&sh[nrow][c8];
    }
  } else if (bid < 544) {
    int idx = (bid - 288) * 1024 + t * 4;
    int which = idx >> 16, off = idx & 65535;
    int m = off >> 8, k = off & 255;
    const float* src = (which == 0) ? Wq : (which == 1) ? Wk
                       : (which == 2) ? Wv : Wo;
    float4 v = *(const float4*)(src + off);
    ushort4 ov;
    ov.x = f2bf(v.x); ov.y = f2bf(v.y); ov.z = f2bf(v.z); ov.w = f2bf(v.w);
    *(ushort4*)(Wb + which * 65536 + swz(m, k)) = ov;
  } else {
    int id = (bid - 544) * 256 + t;
    int flat = id * 8;
    int tile = flat >> 8;
    int within = flat & 255;
    int tm = tile / 144, tq = tile - tm * 144;
    int m = tm * 16 + (within >> 4);
    int q = tq * 16 + (within & 15);
    int ym = div48(m), xm = m - ym * SW;
    int yq = div48(q), xq = q - yq * SW;
    float lam = lam_p[0];
    float dy = (float)(yq - ym);
    float dy2 = dy * dy;
    u16 o[8];
#pragma unroll
    for (int j = 0; j < 8; ++j) {
      float dx = (float)(xq + j - xm);
      o[j] = f2bf(lam * __expf(-sqrtf(dy2 + dx * dx)));
    }
    *(uint4*)(et + flat) = *(const uint4*)o;
  }
}

// ---------------------------------------------------------------------------
// QKV projection, LDS-free MFMA GEMM with swizzled frag loads (R8 structure).
// grid (36, 12, 2), block 256.
__global__ __launch_bounds__(256) void qkv_kernel(
    const u16* __restrict__ Wb, const u16* __restrict__ xt,
    const float* __restrict__ bq, const float* __restrict__ bk,
    const float* __restrict__ bv,
    u16* __restrict__ qt, u16* __restrict__ ktb, u16* __restrict__ vb) {
  int t = threadIdx.x;
  int w = t >> 6, lane = t & 63, lo = lane & 15, quad = lane >> 4;
  int n0 = blockIdx.x * 64;
  int mb = blockIdx.y, b = blockIdx.z;
  int which = mb >> 2;
  int mrel0 = (mb & 3) * 64;
  const u16* A = Wb + which * 65536 + ((mrel0 + w * 16) >> 4) * 4096 + lo * 8;
  const float* bias = (which == 0) ? bq : (which == 1) ? bk : bv;
  const u16* Bx = xt + (size_t)b * HW * DMODEL + lo * 8;

  f32x4 acc[4] = {{0.f, 0.f, 0.f, 0.f}, {0.f, 0.f, 0.f, 0.f},
                  {0.f, 0.f, 0.f, 0.f}, {0.f, 0.f, 0.f, 0.f}};
#pragma unroll
  for (int k0 = 0; k0 < DMODEL; k0 += 32) {
    int kblk = ((k0 >> 3) + quad) << 7;
    short8 af = *(const short8*)(A + kblk);
#pragma unroll
    for (int nt = 0; nt < 4; ++nt) {
      short8 bf_ = *(const short8*)(Bx + ((n0 + nt * 16) >> 4) * 4096 + kblk);
      acc[nt] = __builtin_amdgcn_mfma_f32_16x16x32_bf16(af, bf_, acc[nt], 0, 0, 0);
    }
  }

  int mbase = mrel0 + w * 16 + quad * 4;
  if (which == 2) {
#pragma unroll
    for (int reg = 0; reg < 4; ++reg) {
      int mrel = mbase + reg;
      float bi = bias[mrel];
      u16* dst = vb + (size_t)(b * DMODEL + mrel) * HW + n0 + lo;
#pragma unroll
      for (int nt = 0; nt < 4; ++nt) dst[nt * 16] = f2bf(acc[nt][reg] + bi);
    }
  } else {
    float sc = (which == 0) ? 0.17677669529663687f : 1.0f;
    int h = mbase >> 5, d0 = mbase & 31;
    u16* base = ((which == 0) ? qt : ktb) + (size_t)(b * NHEADS + h) * HW * DK;
    float bi[4], dv[4];
    bool usecos[4], usey[4];
#pragma unroll
    for (int reg = 0; reg < 4; ++reg) {
      int mrel = mbase + reg;
      bi[reg] = bias[mrel];
      int oo = mrel & 127;
      dv[reg] = expf(-0.07195578415606394f * (float)(oo & ~1));
      usecos[reg] = (oo & 1);
      usey[reg] = (mrel >= 128);
    }
#pragma unroll
    for (int nt = 0; nt < 4; ++nt) {
      int n = n0 + nt * 16 + lo;
      int yy = div48(n), xx = n - yy * SW;
      ushort4 ov;
      float vals[4];
#pragma unroll
      for (int reg = 0; reg < 4; ++reg) {
        float tv = (usey[reg] ? (float)yy : (float)xx) * dv[reg];
        float pe = usecos[reg] ? cosf(tv) : sinf(tv);
        vals[reg] = (acc[nt][reg] + bi[reg] + pe) * sc;
      }
      ov.x = f2bf(vals[0]); ov.y = f2bf(vals[1]);
      ov.z = f2bf(vals[2]); ov.w = f2bf(vals[3]);
      *(ushort4*)(base + (size_t)n * DK + d0) = ov;
    }
  }
}

// ---------------------------------------------------------------------------
// MFMA flash attention, S^T + register-resident P, split-K(4), double-buffered
// K/V staging, v_perm truncation packing for P and partial O.
// K staged with permuted rows (R13 derivation): C row (4*quad+reg) of
// instance A/B == key 8*quad+reg / 8*quad+4+reg, so each lane's P is exactly
// the PV B-operand fragment. grid (36, 32, 2): y = h*4+kh. block 256.
__global__ __launch_bounds__(256) void attn_kernel(
    const u16* __restrict__ qt, const u16* __restrict__ ktb,
    const u16* __restrict__ vb, const u16* __restrict__ et,
    u16* __restrict__ po_o, float* __restrict__ po_l) {
  int t = threadIdx.x;
  int w = t >> 6;
  int lane = t & 63;
  int lo = lane & 15, quad = lane >> 4;
  int n0 = blockIdx.x * 64;
  int h = blockIdx.y >> 2, kh = blockIdx.y & 3;
  int b = blockIdx.z;

  __shared__ u16 Ks[2][64 * 40];  // ping-pong permuted-row K tiles
  __shared__ u16 Vs[2][32 * 72];  // ping-pong V^T tiles [d][m]

  const u16* qtg = qt + (size_t)(b * NHEADS + h) * HW * DK;
  const u16* ktg = ktb + (size_t)(b * NHEADS + h) * HW * DK;
  const u16* vbg = vb + (size_t)(b * DMODEL + h * DK) * HW;

  short8 qf = *(const short8*)(qtg + (size_t)(n0 + w * 16 + lo) * DK + quad * 8);

  // staging source-key for this thread's LDS row (permutation applied here)
  int srow = t >> 2;                 // LDS row 0..63
  int sks = srow >> 5, srr = srow & 31;
  int sv = (srr < 16) ? (8 * (srr >> 2) + (srr & 3))
                      : (8 * ((srr - 16) >> 2) + 4 + ((srr - 16) & 3));
  int skey = sks * 32 + sv;          // key offset within 64-tile
  int sc8 = (t & 3) * 8;
  int vdd = t >> 3, vmo = (t & 7) * 8;

  // bias base: Et[tile = tq*144 + tm][q&15=lo, m&15 = 8*(quad&1)+j]
  int tq = (n0 >> 4) + w;
  const u16* etw = et + (size_t)tq * 144 * 256 + lo * 16 + (quad & 1) * 8;
  int qh = quad >> 1;

  f32x4 o0 = {0.f, 0.f, 0.f, 0.f}, o1 = {0.f, 0.f, 0.f, 0.f};
  float lsum = 0.f;

  const int kt0 = kh * 9;
  // prologue: stage tile kt0 into buffer 0
  {
    int m0 = kt0 * 64;
    *(uint4*)&Ks[0][srow * 40 + sc8] =
        *(const uint4*)(ktg + (size_t)(m0 + skey) * DK + sc8);
    *(uint4*)&Vs[0][vdd * 72 + vmo] =
        *(const uint4*)(vbg + (size_t)vdd * HW + m0 + vmo);
  }
  __syncthreads();

  for (int i = 0; i < 9; ++i) {
    int cur = i & 1;
    // stage tile i+1 into the other buffer (no barrier needed: distinct buf)
    if (i + 1 < 9) {
      int m1 = (kt0 + i + 1) * 64;
      *(uint4*)&Ks[cur ^ 1][srow * 40 + sc8] =
          *(const uint4*)(ktg + (size_t)(m1 + skey) * DK + sc8);
      *(uint4*)&Vs[cur ^ 1][vdd * 72 + vmo] =
          *(const uint4*)(vbg + (size_t)vdd * HW + m1 + vmo);
    }

    int m0 = (kt0 + i) * 64;
    // bias loads: one uint4 (8 consecutive E) per lane per 32-key chunk
    uint4 eb0 = *(const uint4*)(etw + (size_t)((m0 >> 4) + 0 + qh) * 256);
    uint4 eb1 = *(const uint4*)(etw + (size_t)((m0 >> 4) + 2 + qh) * 256);

#pragma unroll
    for (int ks = 0; ks < 2; ++ks) {
      uint4 ebv = ks ? eb1 : eb0;
      // S^T: A = permuted K rows, B = Q
      short8 kfA = *(const short8*)&Ks[cur][(ks * 32 + lo) * 40 + quad * 8];
      short8 kfB = *(const short8*)&Ks[cur][(ks * 32 + 16 + lo) * 40 + quad * 8];
      f32x4 z = {0.f, 0.f, 0.f, 0.f};
      f32x4 sA = __builtin_amdgcn_mfma_f32_16x16x32_bf16(kfA, qf, z, 0, 0, 0);
      f32x4 sB = __builtin_amdgcn_mfma_f32_16x16x32_bf16(kfB, qf, z, 0, 0, 0);
      // P = exp(S^T + bias): lane's m = ks*32 + 8*quad + {0..7}, q = lo
      float p0 = __expf(sA[0] + lo2f(ebv.x));
      float p1 = __expf(sA[1] + hi2f(ebv.x));
      float p2 = __expf(sA[2] + lo2f(ebv.y));
      float p3 = __expf(sA[3] + hi2f(ebv.y));
      float p4 = __expf(sB[0] + lo2f(ebv.z));
      float p5 = __expf(sB[1] + hi2f(ebv.z));
      float p6 = __expf(sB[2] + lo2f(ebv.w));
      float p7 = __expf(sB[3] + hi2f(ebv.w));
      lsum += ((p0 + p1) + (p2 + p3)) + ((p4 + p5) + (p6 + p7));
      // pack into PV B-fragment via v_perm truncation (1 op per 2 values)
      unsigned int pk32[4] = {pkbf(p0, p1), pkbf(p2, p3),
                              pkbf(p4, p5), pkbf(p6, p7)};
      short8 pfrag = *(const short8*)pk32;
      // O^T += V^T P^T : A = V^T rows d, B = P (q cols)
      short8 v0 = *(const short8*)&Vs[cur][lo * 72 + ks * 32 + quad * 8];
      o0 = __builtin_amdgcn_mfma_f32_16x16x32_bf16(v0, pfrag, o0, 0, 0, 0);
      short8 v1 = *(const short8*)&Vs[cur][(16 + lo) * 72 + ks * 32 + quad * 8];
      o1 = __builtin_amdgcn_mfma_f32_16x16x32_bf16(v1, pfrag, o1, 0, 0, 0);
    }
    // single barrier: staging of i+1 complete AND compute reads of buf cur
    // done before it is overwritten at iteration i+2
    __syncthreads();
  }

  // full rowsum for q = lo: reduce across the 4 quads
  lsum += __shfl_xor(lsum, 16);
  lsum += __shfl_xor(lsum, 32);

  // store partials (v_perm truncation pack):
  // o0[reg] = O^T[d=4*quad+reg][q=w*16+lo], o1: d+16
  int slot = (b * NHEADS + h) * 36 + blockIdx.x;
  u16* pw = po_o + (size_t)(kh * 576 + slot) * 2048 + w * 512;  // u16 units
  uint2 s0, s1;
  s0.x = pkbf(o0[0], o0[1]); s0.y = pkbf(o0[2], o0[3]);
  s1.x = pkbf(o1[0], o1[1]); s1.y = pkbf(o1[2], o1[3]);
  *(uint2*)(pw + lane * 4) = s0;
  *(uint2*)(pw + 256 + lane * 4) = s1;
  if (quad == 0)
    po_l[(size_t)(kh * 576 + slot) * 64 + w * 16 + lo] = lsum;
}

// ---------------------------------------------------------------------------
// reduce: sum the four split-K partials, normalize, write aot (swizzled).
// Partial semantic: element (lane, reg, half) = O^T[d=4*quad+reg+16*half][q=w*16+lo].
// grid (36, 8, 2), block 256.
__global__ __launch_bounds__(256) void reduce_kernel(
    const u16* __restrict__ po_o, const float* __restrict__ po_l,
    u16* __restrict__ aot) {
  int t = threadIdx.x;
  int w = t >> 6, lane = t & 63, lo = lane & 15, quad = lane >> 4;
  int qt_ = blockIdx.x, h = blockIdx.y, b = blockIdx.z;
  int slot = (b * NHEADS + h) * 36 + qt_;

  float s0[4] = {0.f, 0.f, 0.f, 0.f}, s1[4] = {0.f, 0.f, 0.f, 0.f};
  float lt = 0.f;
#pragma unroll
  for (int kh = 0; kh < 4; ++kh) {
    const u16* p = po_o + (size_t)(kh * 576 + slot) * 2048 + w * 512;
    ushort4 a0 = *(const ushort4*)(p + lane * 4);
    ushort4 a1 = *(const ushort4*)(p + 256 + lane * 4);
    s0[0] += bf2f(a0.x); s0[1] += bf2f(a0.y);
    s0[2] += bf2f(a0.z); s0[3] += bf2f(a0.w);
    s1[0] += bf2f(a1.x); s1[1] += bf2f(a1.y);
    s1[2] += bf2f(a1.z); s1[3] += bf2f(a1.w);
    lt += po_l[(size_t)(kh * 576 + slot) * 64 + w * 16 + lo];
  }
  float inv = 1.0f / lt;

  int n = qt_ * 64 + w * 16 + lo;
  u16* aog = aot + (size_t)b * HW * DMODEL;
  ushort4 w0, w1;
  w0.x = f2bf(s0[0] * inv); w0.y = f2bf(s0[1] * inv);
  w0.z = f2bf(s0[2] * inv); w0.w = f2bf(s0[3] * inv);
  w1.x = f2bf(s1[0] * inv); w1.y = f2bf(s1[1] * inv);
  w1.z = f2bf(s1[2] * inv); w1.w = f2bf(s1[3] * inv);
  *(ushort4*)&aog[swz(n, h * DK + quad * 4)] = w0;
  *(ushort4*)&aog[swz(n, h * DK + 16 + quad * 4)] = w1;
}

// ---------------------------------------------------------------------------
// out[b][c][n] = x + gamma * (Wo ao)[c][n] + bo[c], LDS-free MFMA GEMM with
// swizzled frag loads. grid (36, 4, 2), block 256.
__global__ __launch_bounds__(256) void out_kernel(
    const float* __restrict__ x, const u16* __restrict__ Wob,
    const float* __restrict__ bo, const float* __restrict__ gp,
    const u16* __restrict__ aot, float* __restrict__ out) {
  int t = threadIdx.x;
  int w = t >> 6, lane = t & 63, lo = lane & 15, quad = lane >> 4;
  int n0 = blockIdx.x * 64;
  int c0 = blockIdx.y * 64;
  int b = blockIdx.z;
  float gamma = gp[0];
  const u16* A = Wob + ((c0 + w * 16) >> 4) * 4096 + lo * 8;
  const u16* Ba = aot + (size_t)b * HW * DMODEL + lo * 8;

  f32x4 acc[4] = {{0.f, 0.f, 0.f, 0.f}, {0.f, 0.f, 0.f, 0.f},
                  {0.f, 0.f, 0.f, 0.f}, {0.f, 0.f, 0.f, 0.f}};
#pragma unroll
  for (int k0 = 0; k0 < DMODEL; k0 += 32) {
    int kblk = ((k0 >> 3) + quad) << 7;
    short8 af = *(const short8*)(A + kblk);
#pragma unroll
    for (int nt = 0; nt < 4; ++nt) {
      short8 bf_ = *(const short8*)(Ba + ((n0 + nt * 16) >> 4) * 4096 + kblk);
      acc[nt] = __builtin_amdgcn_mfma_f32_16x16x32_bf16(af, bf_, acc[nt], 0, 0, 0);
    }
  }

#pragma unroll
  for (int reg = 0; reg < 4; ++reg) {
    int c = c0 + w * 16 + quad * 4 + reg;
    float bi = bo[c];
    const float* xs = x + (size_t)(b * DMODEL + c) * HW + n0 + lo;
    float* os = out + (size_t)(b * DMODEL + c) * HW + n0 + lo;
#pragma unroll
    for (int nt = 0; nt < 4; ++nt)
      os[nt * 16] = xs[nt * 16] + gamma * acc[nt][reg] + bi;
  }
}

// ---------------------------------------------------------------------------
extern "C" void kernel_launch(void* const* d_in, const int* in_sizes, int n_in,
                              void* d_out, int out_size, void* d_ws,
                              size_t ws_size, hipStream_t stream) {
  const float* x   = (const float*)d_in[0];
  const float* Wq  = (const float*)d_in[1];
  const float* bq  = (const float*)d_in[2];
  const float* Wk  = (const float*)d_in[3];
  const float* bk  = (const float*)d_in[4];
  const float* Wv  = (const float*)d_in[5];
  const float* bv  = (const float*)d_in[6];
  const float* Wo  = (const float*)d_in[7];
  const float* bo  = (const float*)d_in[8];
  const float* lam = (const float*)d_in[9];
  const float* gam = (const float*)d_in[10];

  // ws layout (bytes); ws_size ~268 MB (R11 fill-dispatch evidence):
  //   (unused)   [0, 36864)
  //   Wb    bf16 [36864, 561152)      4*65536*2, [q|k|v|o], swizzled
  //   xt    bf16 [561152, 2920448)    swizzled; ALIASED with aot
  //   qt    bf16 [2920448, 5279744)
  //   ktb   bf16 [5279744, 7639040)
  //   vb    bf16 [7639040, 9998336)
  //   et    bf16 [9998336, 20615168)  2304*2304 bias, fragment-tile order
  //   po_o  bf16 [20615168, 30052352) split-K(4) partial O
  //   po_l  f32  [30052352, 30642176) split-K(4) partial rowsums
  char* wsb = (char*)d_ws;
  u16* Wb  = (u16*)(wsb + 36864);
  u16* xt  = (u16*)(wsb + 561152);
  u16* aot = xt;  // alias, sequential lifetime
  u16* qt  = (u16*)(wsb + 2920448);
  u16* ktb = (u16*)(wsb + 5279744);
  u16* vb  = (u16*)(wsb + 7639040);
  u16* et  = (u16*)(wsb + 9998336);
  u16* po_o = (u16*)(wsb + 20615168);
  float* po_l = (float*)(wsb + 30052352);
  float* out = (float*)d_out;

  prep_kernel<<<dim3(3136), 256, 0, stream>>>(x, Wq, Wk, Wv, Wo, lam,
                                              xt, Wb, et);
  qkv_kernel<<<dim3(36, 12, BATCH), 256, 0, stream>>>(Wb, xt, bq, bk, bv,
                                                      qt, ktb, vb);
  attn_kernel<<<dim3(36, 32, BATCH), 256, 0, stream>>>(qt, ktb, vb, et,
                                                       po_o, po_l);
  reduce_kernel<<<dim3(36, 8, BATCH), 256, 0, stream>>>(po_o, po_l, aot);
  out_kernel<<<dim3(36, 4, BATCH), 256, 0, stream>>>(x, Wb + 3 * 65536, bo, gam,
                                                     aot, out);
}